// Round 21
// baseline (666.455 us; speedup 1.0000x reference)
//
#include <hip/hip_runtime.h>
#include <hip/hip_bf16.h>
#include <cstdint>
#include <cstddef>

#define NFEAT 512
#define H2 256
#define H3 256
#define H4 128
#define NCLASS 16

typedef __attribute__((ext_vector_type(8))) short short8;
typedef __attribute__((ext_vector_type(4))) float f32x4;
typedef __attribute__((ext_vector_type(4))) unsigned short ushort4v;
typedef __attribute__((ext_vector_type(4))) _Float16 half4v;
typedef __attribute__((ext_vector_type(2))) _Float16 half2v;

#define AS1 __attribute__((address_space(1)))
#define AS3 __attribute__((address_space(3)))

__device__ inline unsigned short f2bf_rne(float x) {
    unsigned int u = __builtin_bit_cast(unsigned int, x);
    unsigned int r = (u + 0x7FFFu + ((u >> 16) & 1u)) >> 16;
    return (unsigned short)r;
}
__device__ inline float bf2f(unsigned short h) {
    return __builtin_bit_cast(float, (unsigned int)h << 16);
}

template <int VM> __device__ __forceinline__ void vm_wait() {
    asm volatile("s_waitcnt vmcnt(%0)" :: "n"(VM) : "memory");
}
__device__ __forceinline__ void lgkm0() {
    asm volatile("s_waitcnt lgkmcnt(0)" ::: "memory");
}

// ---------------- CSR build ----------------
__global__ void k_hist(const int* __restrict__ er, int* __restrict__ cnt, int E) {
    for (int e = blockIdx.x * blockDim.x + threadIdx.x; e < E; e += gridDim.x * blockDim.x)
        atomicAdd(&cnt[er[e]], 1);
}

__global__ void k_scan1(const int* __restrict__ cnt, int* __restrict__ ex,
                        int* __restrict__ bsum, int n) {
    __shared__ int s[256];
    int i = blockIdx.x * 256 + threadIdx.x;
    int v = (i < n) ? cnt[i] : 0;
    s[threadIdx.x] = v;
    __syncthreads();
    #pragma unroll
    for (int off = 1; off < 256; off <<= 1) {
        int t = (threadIdx.x >= (unsigned)off) ? s[threadIdx.x - off] : 0;
        __syncthreads();
        s[threadIdx.x] += t;
        __syncthreads();
    }
    if (i < n) ex[i] = s[threadIdx.x] - v;
    if (threadIdx.x == 255) bsum[blockIdx.x] = s[255];
}

__global__ void k_scan2(int* __restrict__ bsum, int nb) {
    __shared__ int s[512];
    int v = ((int)threadIdx.x < nb) ? bsum[threadIdx.x] : 0;
    s[threadIdx.x] = v;
    __syncthreads();
    #pragma unroll
    for (int off = 1; off < 512; off <<= 1) {
        int t = (threadIdx.x >= (unsigned)off) ? s[threadIdx.x - off] : 0;
        __syncthreads();
        s[threadIdx.x] += t;
        __syncthreads();
    }
    if ((int)threadIdx.x < nb) bsum[threadIdx.x] = s[threadIdx.x] - v;
}

__global__ void k_scan3(int* __restrict__ rp, int* __restrict__ ofs,
                        const int* __restrict__ bsum, const int* __restrict__ cnt,
                        int n) {
    int i = blockIdx.x * 256 + threadIdx.x;
    if (i < n) {
        int v = rp[i] + bsum[blockIdx.x];
        rp[i] = v;
        ofs[i] = v;
        if (i == n - 1) rp[n] = v + cnt[i];
    }
}

// sliced scatter: slice s commits only rows in its N/8 window -> destination
// region (~1.6MB) is L2-resident on its XCD -> full-line writeback, cheap atomics.
__global__ void k_scatter_sl(const int* __restrict__ er, const int* __restrict__ ec,
                             const float* __restrict__ ev, int* __restrict__ ofs,
                             int2* __restrict__ ev2, int E, int sliceSz) {
    const int slice = blockIdx.x & 7;
    const int g = blockIdx.x >> 3;
    const int rlo = slice * sliceSz;
    const int rhi = rlo + sliceSz;
    for (int e = g * 256 + threadIdx.x; e < E; e += 256 * 256) {
        int r = er[e];
        if (r >= rlo && r < rhi) {
            int p = atomicAdd(&ofs[r], 1);
            ev2[p] = make_int2(ec[e], __builtin_bit_cast(int, ev[e]));
        }
    }
}

// ---------------- weight pack: W[K][M] fp32 -> fragment-major bf16 hi/lo ----------------
__global__ __launch_bounds__(256)
void k_packb(const float* __restrict__ W, unsigned short* __restrict__ hi,
             unsigned short* __restrict__ lo, int K, int M) {
    int idx = blockIdx.x * 256 + threadIdx.x;
    int NT = K >> 5;
    int total = (M >> 4) * NT * 64;
    if (idx >= total) return;
    int l = idx & 63;
    int t = (idx >> 6) % NT;
    int cg = idx / (NT << 6);
    int col = cg * 16 + (l & 15);
    int k0 = t * 32 + (l >> 4) * 8;
    short8 h8, l8;
    #pragma unroll
    for (int j = 0; j < 8; ++j) {
        float x = W[(size_t)(k0 + j) * M + col];
        unsigned short h = f2bf_rne(x);
        h8[j] = (short)h;
        l8[j] = (short)f2bf_rne(x - bf2f(h));
    }
    *(short8*)&hi[(size_t)idx * 8] = h8;
    *(short8*)&lo[(size_t)idx * 8] = l8;
}

// ---------------- GEMM1 (counted-vmcnt, 3 fp32 bufs, cooperative convert to
// 2 bf16 dbuf): C16[N,256] = fp16(X[N,512] @ W1). Each element converted ONCE.
__global__ __launch_bounds__(256, 3)
void k_gemm1d(const float* __restrict__ X, const unsigned short* __restrict__ Bh,
              const unsigned short* __restrict__ Bl, _Float16* __restrict__ C16, const int N) {
    constexpr int K = 512, M = 256, NT = K / 32;
    __shared__ char smem[40960];
    float* sXf = (float*)smem;                               // 3 x 2048 fp32 (24 KB)
    unsigned short* sAh = (unsigned short*)(smem + 24576);   // 2 x 2048 bf16 (8 KB)
    unsigned short* sAl = (unsigned short*)(smem + 32768);   // 2 x 2048 bf16 (8 KB)
    const int tid = threadIdx.x;
    const int lane = tid & 63;
    const int w = tid >> 6;
    const int lm = lane & 15, lk = lane >> 4;
    const int row0 = blockIdx.x * 64;
    const int col0 = w * 64;

    const int kseg = (lane & 7) ^ ((lane >> 3) & 7);
    const int r0 = min(row0 + w * 16 + (lane >> 3), N - 1);
    const int r1 = min(row0 + w * 16 + 8 + (lane >> 3), N - 1);
    const size_t ga0 = (size_t)r0 * K + kseg * 4;
    const size_t ga1 = (size_t)r1 * K + kseg * 4;

    const int crow = w * 16 + (lane >> 2);
    const int ch = lane & 3;
    const int cu0 = ((2 * ch) ^ (crow & 7)) * 4;
    const int cu1 = ((2 * ch + 1) ^ (crow & 7)) * 4;
    const int cwo = crow * 32 + (ch ^ (crow & 3)) * 8;

    const unsigned short* bfh = Bh + ((size_t)(w * 4) * NT) * 512 + lane * 8;
    const unsigned short* bfl = Bl + ((size_t)(w * 4) * NT) * 512 + lane * 8;
    const int aoff = lm * 32 + ((lk ^ (lm & 3)) * 8);

    f32x4 acc[4][4];
    #pragma unroll
    for (int i = 0; i < 4; ++i)
        #pragma unroll
        for (int j = 0; j < 4; ++j) acc[i][j] = (f32x4){0.f, 0.f, 0.f, 0.f};

    auto stage = [&](int bi, int kk) {
        __builtin_amdgcn_global_load_lds((const AS1 void*)(X + ga0 + kk),
                                         (AS3 void*)(sXf + bi * 2048 + w * 512), 16, 0, 0);
        __builtin_amdgcn_global_load_lds((const AS1 void*)(X + ga1 + kk),
                                         (AS3 void*)(sXf + bi * 2048 + w * 512 + 256), 16, 0, 0);
    };

    auto convert = [&](int src, int dst) {
        const float* s = sXf + src * 2048 + crow * 32;
        f32x4 p0 = *(const f32x4*)(s + cu0);
        f32x4 p1 = *(const f32x4*)(s + cu1);
        float vv[8] = {p0.x, p0.y, p0.z, p0.w, p1.x, p1.y, p1.z, p1.w};
        short8 ah, al;
        #pragma unroll
        for (int j = 0; j < 8; ++j) {
            unsigned int uu = __builtin_bit_cast(unsigned int, vv[j]);
            ah[j] = (short)(uu >> 16);
            float hi_ = __builtin_bit_cast(float, uu & 0xFFFF0000u);
            al[j] = (short)f2bf_rne(vv[j] - hi_);
        }
        *(short8*)&sAh[dst * 2048 + cwo] = ah;
        *(short8*)&sAl[dst * 2048 + cwo] = al;
    };

    stage(0, 0); stage(1, 32); stage(2, 64);
    short8 bhf[4], blf[4];
    #pragma unroll
    for (int nf = 0; nf < 4; ++nf) {
        const size_t o = (size_t)nf * NT * 512;
        bhf[nf] = *(const short8*)(bfh + o);
        blf[nf] = *(const short8*)(bfl + o);
    }
    vm_wait<12>();
    convert(0, 0);
    lgkm0();
    __builtin_amdgcn_s_barrier();

    int b0 = 0;

#define G1D_BODY(T, VM)                                                         \
    {                                                                           \
        vm_wait<VM>();                                                          \
        __builtin_amdgcn_s_barrier();                                           \
        __builtin_amdgcn_sched_barrier(0);                                      \
        short8 bhn[4], bln[4];                                                  \
        _Pragma("unroll")                                                       \
        for (int nf = 0; nf < 4; ++nf) { bhn[nf] = bhf[nf]; bln[nf] = blf[nf]; }\
        if ((T) + 1 < NT) {                                                     \
            _Pragma("unroll")                                                   \
            for (int nf = 0; nf < 4; ++nf) {                                    \
                const size_t o = ((size_t)nf * NT + (T) + 1) * 512;             \
                bhn[nf] = *(const short8*)(bfh + o);                            \
                bln[nf] = *(const short8*)(bfl + o);                            \
            }                                                                   \
        }                                                                       \
        __builtin_amdgcn_sched_barrier(0);                                      \
        _Pragma("unroll")                                                       \
        for (int mf = 0; mf < 4; ++mf) {                                        \
            short8 ah = *(const short8*)&sAh[((T) & 1) * 2048 + aoff + mf * 512]; \
            short8 al = *(const short8*)&sAl[((T) & 1) * 2048 + aoff + mf * 512]; \
            _Pragma("unroll")                                                   \
            for (int nf = 0; nf < 4; ++nf) {                                    \
                acc[mf][nf] = __builtin_amdgcn_mfma_f32_16x16x32_bf16(ah, bhf[nf], acc[mf][nf], 0, 0, 0); \
                acc[mf][nf] = __builtin_amdgcn_mfma_f32_16x16x32_bf16(ah, blf[nf], acc[mf][nf], 0, 0, 0); \
                acc[mf][nf] = __builtin_amdgcn_mfma_f32_16x16x32_bf16(al, bhf[nf], acc[mf][nf], 0, 0, 0); \
            }                                                                   \
        }                                                                       \
        if ((T) + 1 < NT) {                                                     \
            int src = b0 + 1; if (src == 3) src = 0;                            \
            convert(src, ((T) + 1) & 1);                                        \
        }                                                                       \
        lgkm0();                                                                \
        __builtin_amdgcn_sched_barrier(0);                                      \
        __builtin_amdgcn_s_barrier();                                           \
        if ((T) + 3 < NT) stage(b0, ((T) + 3) * 32);                            \
        _Pragma("unroll")                                                       \
        for (int nf = 0; nf < 4; ++nf) { bhf[nf] = bhn[nf]; blf[nf] = bln[nf]; }\
        b0 = b0 + 1; if (b0 == 3) b0 = 0;                                       \
    }

    for (int t = 0; t < NT - 2; ++t) G1D_BODY(t, 10);
    G1D_BODY(NT - 2, 8);
    G1D_BODY(NT - 1, 8);
#undef G1D_BODY

    float* sc = (float*)smem;
    #pragma unroll
    for (int mf = 0; mf < 4; ++mf) {
        __syncthreads();
        #pragma unroll
        for (int nf = 0; nf < 4; ++nf)
            #pragma unroll
            for (int r = 0; r < 4; ++r) {
                const int rl = lk * 4 + r;
                const int col = col0 + nf * 16 + lm;
                sc[rl * M + (col ^ (lk << 3))] = acc[mf][nf][r];
            }
        __syncthreads();
        #pragma unroll
        for (int i = 0; i < 4; ++i) {
            const int idx = i * 256 + tid;
            const int rl = idx >> 6, u = idx & 63;
            const int grow = row0 + mf * 16 + rl;
            if (grow < N) {
                f32x4 v = *(const f32x4*)&sc[rl * M + ((u * 4) ^ (((rl >> 2) & 3) << 3))];
                half4v h;
                h[0] = (_Float16)v[0]; h[1] = (_Float16)v[1];
                h[2] = (_Float16)v[2]; h[3] = (_Float16)v[3];
                *(half4v*)&C16[(size_t)grow * M + u * 4] = h;
            }
        }
    }
}

// ---------------- GEMM (A pre-split bf16 h/l), counted-vmcnt 3-buf, fp16 out ----------------
template <int K, int NFW>
__global__ __launch_bounds__(256, 3)
void k_gemm_btc(const unsigned short* __restrict__ Ah, const unsigned short* __restrict__ Al,
                const unsigned short* __restrict__ Bh, const unsigned short* __restrict__ Bl,
                _Float16* __restrict__ C16, const int N) {
    constexpr int M = 64 * NFW;
    constexpr int NT = K / 32;
    constexpr int UPR = 16 * NFW;
    __shared__ char smem[24576];
    unsigned short* sAh = (unsigned short*)smem;          // [3][2048]
    unsigned short* sAl = sAh + 6144;                     // [3][2048]
    const int tid = threadIdx.x;
    const int lane = tid & 63;
    const int w = tid >> 6;
    const int lm = lane & 15, lk = lane >> 4;
    const int row0 = blockIdx.x * 64;
    const int col0 = w * (16 * NFW);

    const int kseg = (lane & 3) ^ ((lane >> 2) & 3);
    const int gr = min(row0 + w * 16 + (lane >> 2), N - 1);
    const size_t ga = (size_t)gr * K + kseg * 8;

    const int aoff = lm * 32 + ((lk ^ (lm & 3)) * 8);

    const unsigned short* bfh = Bh + ((size_t)(w * NFW) * NT) * 512 + lane * 8;
    const unsigned short* bfl = Bl + ((size_t)(w * NFW) * NT) * 512 + lane * 8;

    f32x4 acc[4][NFW];
    #pragma unroll
    for (int i = 0; i < 4; ++i)
        #pragma unroll
        for (int j = 0; j < NFW; ++j) acc[i][j] = (f32x4){0.f, 0.f, 0.f, 0.f};

    auto stage = [&](int bi, int kk) {
        __builtin_amdgcn_global_load_lds((const AS1 void*)(Ah + ga + kk),
                                         (AS3 void*)(sAh + bi * 2048 + w * 512), 16, 0, 0);
        __builtin_amdgcn_global_load_lds((const AS1 void*)(Al + ga + kk),
                                         (AS3 void*)(sAl + bi * 2048 + w * 512), 16, 0, 0);
    };

    stage(0, 0); stage(1, 32); stage(2, 64);

    short8 bhf[NFW], blf[NFW];
    #pragma unroll
    for (int nf = 0; nf < NFW; ++nf) {
        const size_t o = (size_t)nf * NT * 512;
        bhf[nf] = *(const short8*)(bfh + o);
        blf[nf] = *(const short8*)(bfl + o);
    }

    int bi = 0;

#define GBT_BODY(T, VM)                                                         \
    {                                                                           \
        vm_wait<VM>();                                                          \
        __builtin_amdgcn_s_barrier();                                           \
        __builtin_amdgcn_sched_barrier(0);                                      \
        short8 bhn[NFW], bln[NFW];                                              \
        _Pragma("unroll")                                                       \
        for (int nf = 0; nf < NFW; ++nf) { bhn[nf] = bhf[nf]; bln[nf] = blf[nf]; } \
        if ((T) + 1 < NT) {                                                     \
            _Pragma("unroll")                                                   \
            for (int nf = 0; nf < NFW; ++nf) {                                  \
                const size_t o = ((size_t)nf * NT + (T) + 1) * 512;             \
                bhn[nf] = *(const short8*)(bfh + o);                            \
                bln[nf] = *(const short8*)(bfl + o);                            \
            }                                                                   \
        }                                                                       \
        __builtin_amdgcn_sched_barrier(0);                                      \
        _Pragma("unroll")                                                       \
        for (int mf = 0; mf < 4; ++mf) {                                        \
            short8 ah = *(const short8*)&sAh[bi * 2048 + aoff + mf * 512];      \
            short8 al = *(const short8*)&sAl[bi * 2048 + aoff + mf * 512];      \
            _Pragma("unroll")                                                   \
            for (int nf = 0; nf < NFW; ++nf) {                                  \
                acc[mf][nf] = __builtin_amdgcn_mfma_f32_16x16x32_bf16(ah, bhf[nf], acc[mf][nf], 0, 0, 0); \
                acc[mf][nf] = __builtin_amdgcn_mfma_f32_16x16x32_bf16(ah, blf[nf], acc[mf][nf], 0, 0, 0); \
                acc[mf][nf] = __builtin_amdgcn_mfma_f32_16x16x32_bf16(al, bhf[nf], acc[mf][nf], 0, 0, 0); \
            }                                                                   \
        }                                                                       \
        lgkm0();                                                                \
        __builtin_amdgcn_sched_barrier(0);                                      \
        __builtin_amdgcn_s_barrier();                                           \
        if ((T) + 3 < NT) stage(bi, ((T) + 3) * 32);                            \
        _Pragma("unroll")                                                       \
        for (int nf = 0; nf < NFW; ++nf) { bhf[nf] = bhn[nf]; blf[nf] = bln[nf]; } \
        bi = bi + 1; if (bi == 3) bi = 0;                                       \
    }

    for (int t = 0; t < NT - 2; ++t) GBT_BODY(t, 2 * NFW + 4);
    GBT_BODY(NT - 2, 2 * NFW + 2);
    GBT_BODY(NT - 1, 2 * NFW);
#undef GBT_BODY

    float* sc = (float*)smem;
    #pragma unroll
    for (int mf = 0; mf < 4; ++mf) {
        __syncthreads();
        #pragma unroll
        for (int nf = 0; nf < NFW; ++nf)
            #pragma unroll
            for (int r = 0; r < 4; ++r) {
                const int rl = lk * 4 + r;
                const int col = col0 + nf * 16 + lm;
                sc[rl * M + (col ^ (lk << 3))] = acc[mf][nf][r];
            }
        __syncthreads();
        #pragma unroll
        for (int i = 0; i < (16 * UPR) / 256; ++i) {
            const int idx = i * 256 + tid;
            const int rl = idx / UPR, u = idx % UPR;
            const int grow = row0 + mf * 16 + rl;
            if (grow < N) {
                f32x4 v = *(const f32x4*)&sc[rl * M + ((u * 4) ^ (((rl >> 2) & 3) << 3))];
                half4v h;
                h[0] = (_Float16)v[0]; h[1] = (_Float16)v[1];
                h[2] = (_Float16)v[2]; h[3] = (_Float16)v[3];
                *(half4v*)&C16[(size_t)grow * M + u * 4] = h;
            }
        }
    }
}

// ---------------- SpMM on fp16 input (F=256), wave-per-row, fused bias+relu+split.
// Streaming IO (ev2, outputs) is NONTEMPORAL so L3 retains the gathered C16.
__global__ __launch_bounds__(256)
void k_spmm256f(const int* __restrict__ rp, const int2* __restrict__ ev2,
                const _Float16* __restrict__ in16, const float* __restrict__ bias,
                unsigned short* __restrict__ oh, unsigned short* __restrict__ ol, int N) {
    const int lane = threadIdx.x & 63;
    int r = __builtin_amdgcn_readfirstlane(blockIdx.x * 4 + (threadIdx.x >> 6));
    if (r >= N) return;
    const int e0 = __builtin_amdgcn_readfirstlane(rp[r]);
    const int e1 = __builtin_amdgcn_readfirstlane(rp[r + 1]);
    f32x4 acc = {0.f, 0.f, 0.f, 0.f};
    const _Float16* base = in16 + lane * 4;

    #pragma unroll 4
    for (int e = e0; e < e1; ++e) {
        long long pe = __builtin_nontemporal_load((const long long*)(ev2 + e));
        int col = (int)(unsigned int)(pe & 0xFFFFFFFFll);
        float val = __builtin_bit_cast(float, (int)(pe >> 32));
        half4v hv = *(const half4v*)(base + (size_t)col * 256);
        acc[0] = fmaf(val, (float)hv[0], acc[0]);
        acc[1] = fmaf(val, (float)hv[1], acc[1]);
        acc[2] = fmaf(val, (float)hv[2], acc[2]);
        acc[3] = fmaf(val, (float)hv[3], acc[3]);
    }

    f32x4 bv = *(const f32x4*)&bias[lane * 4];
    ushort4v h, l;
    #pragma unroll
    for (int j = 0; j < 4; ++j) {
        float o = fmaxf(acc[j] + bv[j], 0.f);
        unsigned short hh = f2bf_rne(o);
        h[j] = hh;
        l[j] = f2bf_rne(o - bf2f(hh));
    }
    __builtin_nontemporal_store(h, (ushort4v*)&oh[(size_t)r * 256 + lane * 4]);
    __builtin_nontemporal_store(l, (ushort4v*)&ol[(size_t)r * 256 + lane * 4]);
}

// ---------------- SpMM F=128 on fp16 input + fused bias/relu + final dense ----------------
__global__ __launch_bounds__(256)
void k_spmm128f(const int* __restrict__ rp, const int2* __restrict__ ev2,
                const _Float16* __restrict__ in16, const float* __restrict__ b3,
                const float* __restrict__ Wd, const float* __restrict__ bd,
                float* __restrict__ out, int N) {
    __shared__ float Ws[H4 * NCLASS];
    __shared__ float hrow[4][H4];
    {
        int i = threadIdx.x * 8;
        *(f32x4*)&Ws[i] = *(const f32x4*)&Wd[i];
        *(f32x4*)&Ws[i + 4] = *(const f32x4*)&Wd[i + 4];
    }
    __syncthreads();

    const int lane = threadIdx.x & 63;
    const int w = threadIdx.x >> 6;
    int r = __builtin_amdgcn_readfirstlane(blockIdx.x * 4 + w);
    if (r >= N) return;
    const int e0 = __builtin_amdgcn_readfirstlane(rp[r]);
    const int e1 = __builtin_amdgcn_readfirstlane(rp[r + 1]);
    float a0 = 0.f, a1 = 0.f;
    const _Float16* base = in16 + lane * 2;

    #pragma unroll 4
    for (int e = e0; e < e1; ++e) {
        long long pe = __builtin_nontemporal_load((const long long*)(ev2 + e));
        int col = (int)(unsigned int)(pe & 0xFFFFFFFFll);
        float v = __builtin_bit_cast(float, (int)(pe >> 32));
        half2v hv = *(const half2v*)(base + (size_t)col * 128);
        a0 = fmaf(v, (float)hv[0], a0);
        a1 = fmaf(v, (float)hv[1], a1);
    }

    float2 hb;
    hb.x = fmaxf(a0 + b3[lane * 2 + 0], 0.f);
    hb.y = fmaxf(a1 + b3[lane * 2 + 1], 0.f);
    *(float2*)&hrow[w][lane * 2] = hb;

    const int c = lane & 15, q = lane >> 4;
    float s = 0.f;
    #pragma unroll
    for (int k = q * 32; k < q * 32 + 32; ++k)
        s = fmaf(hrow[w][k], Ws[k * NCLASS + c], s);
    s += __shfl_xor(s, 16);
    s += __shfl_xor(s, 32);
    if (lane < 16) {
        float o = s + bd[lane];
        __builtin_nontemporal_store(o, &out[(size_t)r * NCLASS + lane]);
    }
}

extern "C" void kernel_launch(void* const* d_in, const int* in_sizes, int n_in,
                              void* d_out, int out_size, void* d_ws, size_t ws_size,
                              hipStream_t stream) {
    const float* x  = (const float*)d_in[0];
    const int*   er = (const int*)d_in[1];
    const int*   ec = (const int*)d_in[2];
    const float* ev = (const float*)d_in[3];
    const float* W1 = (const float*)d_in[4];
    const float* b1 = (const float*)d_in[5];
    const float* W2 = (const float*)d_in[6];
    const float* b2 = (const float*)d_in[7];
    const float* W3 = (const float*)d_in[8];
    const float* b3 = (const float*)d_in[9];
    const float* Wd = (const float*)d_in[10];
    const float* bd = (const float*)d_in[11];
    float* out = (float*)d_out;

    const int N = in_sizes[0] / NFEAT;
    const int E = in_sizes[1];

    char* w = (char*)d_ws;
    auto alloc = [&](size_t bytes) { char* p = w; w += (bytes + 255) & ~(size_t)255; return p; };
    _Float16* C16 = (_Float16*)alloc((size_t)N * 256 * 2);
    unsigned short* hh = (unsigned short*)alloc((size_t)N * 256 * 2);
    unsigned short* hl = (unsigned short*)alloc((size_t)N * 256 * 2);
    int* cnt  = (int*)alloc((size_t)N * 4);
    int* rp   = (int*)alloc((size_t)(N + 1) * 4);
    int* ofs  = (int*)alloc((size_t)N * 4);
    int2* ev2 = (int2*)alloc((size_t)E * 8);
    int* bsum = (int*)alloc(4096);
    unsigned short* W1h = (unsigned short*)alloc((size_t)NFEAT * H2 * 2);
    unsigned short* W1l = (unsigned short*)alloc((size_t)NFEAT * H2 * 2);
    unsigned short* W2h = (unsigned short*)alloc((size_t)H2 * H3 * 2);
    unsigned short* W2l = (unsigned short*)alloc((size_t)H2 * H3 * 2);
    unsigned short* W3h = (unsigned short*)alloc((size_t)H3 * H4 * 2);
    unsigned short* W3l = (unsigned short*)alloc((size_t)H3 * H4 * 2);

    const int nb = (N + 255) / 256;
    const int sliceSz = (N + 7) / 8;

    hipMemsetAsync(cnt, 0, (size_t)N * 4, stream);
    k_hist<<<1024, 256, 0, stream>>>(er, cnt, E);
    k_scan1<<<nb, 256, 0, stream>>>(cnt, rp, bsum, N);
    k_scan2<<<1, 512, 0, stream>>>(bsum, nb);
    k_scan3<<<nb, 256, 0, stream>>>(rp, ofs, bsum, cnt, N);
    k_scatter_sl<<<2048, 256, 0, stream>>>(er, ec, ev, ofs, ev2, E, sliceSz);

    k_packb<<<(NFEAT * H2 / 8 + 255) / 256, 256, 0, stream>>>(W1, W1h, W1l, NFEAT, H2);
    k_packb<<<(H2 * H3 / 8 + 255) / 256, 256, 0, stream>>>(W2, W2h, W2l, H2, H3);
    k_packb<<<(H3 * H4 / 8 + 255) / 256, 256, 0, stream>>>(W3, W3h, W3l, H3, H4);

    const int rgrid = (N + 63) / 64;
    const int sgrid = (N + 3) / 4;

    k_gemm1d<<<rgrid, 256, 0, stream>>>(x, W1h, W1l, C16, N);
    k_spmm256f<<<sgrid, 256, 0, stream>>>(rp, ev2, C16, b1, hh, hl, N);

    k_gemm_btc<H2, 4><<<rgrid, 256, 0, stream>>>(hh, hl, W2h, W2l, C16, N);
    k_spmm256f<<<sgrid, 256, 0, stream>>>(rp, ev2, C16, b2, hh, hl, N);

    k_gemm_btc<H3, 2><<<rgrid, 256, 0, stream>>>(hh, hl, W3h, W3l, C16, N);
    k_spmm128f<<<sgrid, 256, 0, stream>>>(rp, ev2, C16, b3, Wd, bd, out, N);
}

// Round 22
// 650.069 us; speedup vs baseline: 1.0252x; 1.0252x over previous
//
#include <hip/hip_runtime.h>
#include <hip/hip_bf16.h>
#include <cstdint>
#include <cstddef>

#define NFEAT 512
#define H2 256
#define H3 256
#define H4 128
#define NCLASS 16

typedef __attribute__((ext_vector_type(8))) short short8;
typedef __attribute__((ext_vector_type(4))) float f32x4;
typedef __attribute__((ext_vector_type(4))) unsigned short ushort4v;
typedef __attribute__((ext_vector_type(4))) _Float16 half4v;
typedef __attribute__((ext_vector_type(2))) _Float16 half2v;

#define AS1 __attribute__((address_space(1)))
#define AS3 __attribute__((address_space(3)))

__device__ inline unsigned short f2bf_rne(float x) {
    unsigned int u = __builtin_bit_cast(unsigned int, x);
    unsigned int r = (u + 0x7FFFu + ((u >> 16) & 1u)) >> 16;
    return (unsigned short)r;
}
__device__ inline float bf2f(unsigned short h) {
    return __builtin_bit_cast(float, (unsigned int)h << 16);
}

template <int VM> __device__ __forceinline__ void vm_wait() {
    asm volatile("s_waitcnt vmcnt(%0)" :: "n"(VM) : "memory");
}
__device__ __forceinline__ void lgkm0() {
    asm volatile("s_waitcnt lgkmcnt(0)" ::: "memory");
}

// ---------------- CSR build ----------------
__global__ void k_hist(const int* __restrict__ er, int* __restrict__ cnt, int E) {
    for (int e = blockIdx.x * blockDim.x + threadIdx.x; e < E; e += gridDim.x * blockDim.x)
        atomicAdd(&cnt[er[e]], 1);
}

__global__ void k_scan1(const int* __restrict__ cnt, int* __restrict__ ex,
                        int* __restrict__ bsum, int n) {
    __shared__ int s[256];
    int i = blockIdx.x * 256 + threadIdx.x;
    int v = (i < n) ? cnt[i] : 0;
    s[threadIdx.x] = v;
    __syncthreads();
    #pragma unroll
    for (int off = 1; off < 256; off <<= 1) {
        int t = (threadIdx.x >= (unsigned)off) ? s[threadIdx.x - off] : 0;
        __syncthreads();
        s[threadIdx.x] += t;
        __syncthreads();
    }
    if (i < n) ex[i] = s[threadIdx.x] - v;
    if (threadIdx.x == 255) bsum[blockIdx.x] = s[255];
}

__global__ void k_scan2(int* __restrict__ bsum, int nb) {
    __shared__ int s[512];
    int v = ((int)threadIdx.x < nb) ? bsum[threadIdx.x] : 0;
    s[threadIdx.x] = v;
    __syncthreads();
    #pragma unroll
    for (int off = 1; off < 512; off <<= 1) {
        int t = (threadIdx.x >= (unsigned)off) ? s[threadIdx.x - off] : 0;
        __syncthreads();
        s[threadIdx.x] += t;
        __syncthreads();
    }
    if ((int)threadIdx.x < nb) bsum[threadIdx.x] = s[threadIdx.x] - v;
}

__global__ void k_scan3(int* __restrict__ rp, int* __restrict__ ofs,
                        const int* __restrict__ bsum, const int* __restrict__ cnt,
                        int n) {
    int i = blockIdx.x * 256 + threadIdx.x;
    if (i < n) {
        int v = rp[i] + bsum[blockIdx.x];
        rp[i] = v;
        ofs[i] = v;
        if (i == n - 1) rp[n] = v + cnt[i];
    }
}

// sliced scatter: slice s commits only rows in its N/8 window -> destination
// region (~1.6MB) is L2-resident on its XCD -> full-line writeback, cheap atomics.
__global__ void k_scatter_sl(const int* __restrict__ er, const int* __restrict__ ec,
                             const float* __restrict__ ev, int* __restrict__ ofs,
                             int2* __restrict__ ev2, int E, int sliceSz) {
    const int slice = blockIdx.x & 7;
    const int g = blockIdx.x >> 3;
    const int rlo = slice * sliceSz;
    const int rhi = rlo + sliceSz;
    for (int e = g * 256 + threadIdx.x; e < E; e += 256 * 256) {
        int r = er[e];
        if (r >= rlo && r < rhi) {
            int p = atomicAdd(&ofs[r], 1);
            ev2[p] = make_int2(ec[e], __builtin_bit_cast(int, ev[e]));
        }
    }
}

// ---------------- weight pack: W[K][M] fp32 -> fragment-major bf16 hi/lo ----------------
__global__ __launch_bounds__(256)
void k_packb(const float* __restrict__ W, unsigned short* __restrict__ hi,
             unsigned short* __restrict__ lo, int K, int M) {
    int idx = blockIdx.x * 256 + threadIdx.x;
    int NT = K >> 5;
    int total = (M >> 4) * NT * 64;
    if (idx >= total) return;
    int l = idx & 63;
    int t = (idx >> 6) % NT;
    int cg = idx / (NT << 6);
    int col = cg * 16 + (l & 15);
    int k0 = t * 32 + (l >> 4) * 8;
    short8 h8, l8;
    #pragma unroll
    for (int j = 0; j < 8; ++j) {
        float x = W[(size_t)(k0 + j) * M + col];
        unsigned short h = f2bf_rne(x);
        h8[j] = (short)h;
        l8[j] = (short)f2bf_rne(x - bf2f(h));
    }
    *(short8*)&hi[(size_t)idx * 8] = h8;
    *(short8*)&lo[(size_t)idx * 8] = l8;
}

// ---------------- GEMM1 (counted-vmcnt, 3 fp32 bufs, cooperative convert to
// 2 bf16 dbuf): C16[N,256] = fp16(X[N,512] @ W1). Each element converted ONCE.
__global__ __launch_bounds__(256, 3)
void k_gemm1d(const float* __restrict__ X, const unsigned short* __restrict__ Bh,
              const unsigned short* __restrict__ Bl, _Float16* __restrict__ C16, const int N) {
    constexpr int K = 512, M = 256, NT = K / 32;
    __shared__ char smem[40960];
    float* sXf = (float*)smem;                               // 3 x 2048 fp32 (24 KB)
    unsigned short* sAh = (unsigned short*)(smem + 24576);   // 2 x 2048 bf16 (8 KB)
    unsigned short* sAl = (unsigned short*)(smem + 32768);   // 2 x 2048 bf16 (8 KB)
    const int tid = threadIdx.x;
    const int lane = tid & 63;
    const int w = tid >> 6;
    const int lm = lane & 15, lk = lane >> 4;
    const int row0 = blockIdx.x * 64;
    const int col0 = w * 64;

    const int kseg = (lane & 7) ^ ((lane >> 3) & 7);
    const int r0 = min(row0 + w * 16 + (lane >> 3), N - 1);
    const int r1 = min(row0 + w * 16 + 8 + (lane >> 3), N - 1);
    const size_t ga0 = (size_t)r0 * K + kseg * 4;
    const size_t ga1 = (size_t)r1 * K + kseg * 4;

    const int crow = w * 16 + (lane >> 2);
    const int ch = lane & 3;
    const int cu0 = ((2 * ch) ^ (crow & 7)) * 4;
    const int cu1 = ((2 * ch + 1) ^ (crow & 7)) * 4;
    const int cwo = crow * 32 + (ch ^ (crow & 3)) * 8;

    const unsigned short* bfh = Bh + ((size_t)(w * 4) * NT) * 512 + lane * 8;
    const unsigned short* bfl = Bl + ((size_t)(w * 4) * NT) * 512 + lane * 8;
    const int aoff = lm * 32 + ((lk ^ (lm & 3)) * 8);

    f32x4 acc[4][4];
    #pragma unroll
    for (int i = 0; i < 4; ++i)
        #pragma unroll
        for (int j = 0; j < 4; ++j) acc[i][j] = (f32x4){0.f, 0.f, 0.f, 0.f};

    auto stage = [&](int bi, int kk) {
        __builtin_amdgcn_global_load_lds((const AS1 void*)(X + ga0 + kk),
                                         (AS3 void*)(sXf + bi * 2048 + w * 512), 16, 0, 0);
        __builtin_amdgcn_global_load_lds((const AS1 void*)(X + ga1 + kk),
                                         (AS3 void*)(sXf + bi * 2048 + w * 512 + 256), 16, 0, 0);
    };

    auto convert = [&](int src, int dst) {
        const float* s = sXf + src * 2048 + crow * 32;
        f32x4 p0 = *(const f32x4*)(s + cu0);
        f32x4 p1 = *(const f32x4*)(s + cu1);
        float vv[8] = {p0.x, p0.y, p0.z, p0.w, p1.x, p1.y, p1.z, p1.w};
        short8 ah, al;
        #pragma unroll
        for (int j = 0; j < 8; ++j) {
            unsigned int uu = __builtin_bit_cast(unsigned int, vv[j]);
            ah[j] = (short)(uu >> 16);
            float hi_ = __builtin_bit_cast(float, uu & 0xFFFF0000u);
            al[j] = (short)f2bf_rne(vv[j] - hi_);
        }
        *(short8*)&sAh[dst * 2048 + cwo] = ah;
        *(short8*)&sAl[dst * 2048 + cwo] = al;
    };

    stage(0, 0); stage(1, 32); stage(2, 64);
    short8 bhf[4], blf[4];
    #pragma unroll
    for (int nf = 0; nf < 4; ++nf) {
        const size_t o = (size_t)nf * NT * 512;
        bhf[nf] = *(const short8*)(bfh + o);
        blf[nf] = *(const short8*)(bfl + o);
    }
    vm_wait<12>();
    convert(0, 0);
    lgkm0();
    __builtin_amdgcn_s_barrier();

    int b0 = 0;

#define G1D_BODY(T, VM)                                                         \
    {                                                                           \
        vm_wait<VM>();                                                          \
        __builtin_amdgcn_s_barrier();                                           \
        __builtin_amdgcn_sched_barrier(0);                                      \
        short8 bhn[4], bln[4];                                                  \
        _Pragma("unroll")                                                       \
        for (int nf = 0; nf < 4; ++nf) { bhn[nf] = bhf[nf]; bln[nf] = blf[nf]; }\
        if ((T) + 1 < NT) {                                                     \
            _Pragma("unroll")                                                   \
            for (int nf = 0; nf < 4; ++nf) {                                    \
                const size_t o = ((size_t)nf * NT + (T) + 1) * 512;             \
                bhn[nf] = *(const short8*)(bfh + o);                            \
                bln[nf] = *(const short8*)(bfl + o);                            \
            }                                                                   \
        }                                                                       \
        __builtin_amdgcn_sched_barrier(0);                                      \
        _Pragma("unroll")                                                       \
        for (int mf = 0; mf < 4; ++mf) {                                        \
            short8 ah = *(const short8*)&sAh[((T) & 1) * 2048 + aoff + mf * 512]; \
            short8 al = *(const short8*)&sAl[((T) & 1) * 2048 + aoff + mf * 512]; \
            _Pragma("unroll")                                                   \
            for (int nf = 0; nf < 4; ++nf) {                                    \
                acc[mf][nf] = __builtin_amdgcn_mfma_f32_16x16x32_bf16(ah, bhf[nf], acc[mf][nf], 0, 0, 0); \
                acc[mf][nf] = __builtin_amdgcn_mfma_f32_16x16x32_bf16(ah, blf[nf], acc[mf][nf], 0, 0, 0); \
                acc[mf][nf] = __builtin_amdgcn_mfma_f32_16x16x32_bf16(al, bhf[nf], acc[mf][nf], 0, 0, 0); \
            }                                                                   \
        }                                                                       \
        if ((T) + 1 < NT) {                                                     \
            int src = b0 + 1; if (src == 3) src = 0;                            \
            convert(src, ((T) + 1) & 1);                                        \
        }                                                                       \
        lgkm0();                                                                \
        __builtin_amdgcn_sched_barrier(0);                                      \
        __builtin_amdgcn_s_barrier();                                           \
        if ((T) + 3 < NT) stage(b0, ((T) + 3) * 32);                            \
        _Pragma("unroll")                                                       \
        for (int nf = 0; nf < 4; ++nf) { bhf[nf] = bhn[nf]; blf[nf] = bln[nf]; }\
        b0 = b0 + 1; if (b0 == 3) b0 = 0;                                       \
    }

    for (int t = 0; t < NT - 2; ++t) G1D_BODY(t, 10);
    G1D_BODY(NT - 2, 8);
    G1D_BODY(NT - 1, 8);
#undef G1D_BODY

    float* sc = (float*)smem;
    #pragma unroll
    for (int mf = 0; mf < 4; ++mf) {
        __syncthreads();
        #pragma unroll
        for (int nf = 0; nf < 4; ++nf)
            #pragma unroll
            for (int r = 0; r < 4; ++r) {
                const int rl = lk * 4 + r;
                const int col = col0 + nf * 16 + lm;
                sc[rl * M + (col ^ (lk << 3))] = acc[mf][nf][r];
            }
        __syncthreads();
        #pragma unroll
        for (int i = 0; i < 4; ++i) {
            const int idx = i * 256 + tid;
            const int rl = idx >> 6, u = idx & 63;
            const int grow = row0 + mf * 16 + rl;
            if (grow < N) {
                f32x4 v = *(const f32x4*)&sc[rl * M + ((u * 4) ^ (((rl >> 2) & 3) << 3))];
                half4v h;
                h[0] = (_Float16)v[0]; h[1] = (_Float16)v[1];
                h[2] = (_Float16)v[2]; h[3] = (_Float16)v[3];
                *(half4v*)&C16[(size_t)grow * M + u * 4] = h;
            }
        }
    }
}

// ---------------- GEMM with fp16 A (counted-vmcnt, 3 fp16 bufs, cooperative
// convert to 2 bf16 dbuf): C16out = fp16(A16 @ W). One stage load per wave.
template <int K, int NFW>
__global__ __launch_bounds__(256, 3)
void k_gemm_f16a(const _Float16* __restrict__ A16, const unsigned short* __restrict__ Bh,
                 const unsigned short* __restrict__ Bl, _Float16* __restrict__ Cout,
                 const int N) {
    constexpr int M = 64 * NFW;
    constexpr int NT = K / 32;
    constexpr int UPR = 16 * NFW;
    __shared__ char smem[28672];
    _Float16* sX16 = (_Float16*)smem;                        // 3 x 2048 halves (12 KB)
    unsigned short* sAh = (unsigned short*)(smem + 12288);   // 2 x 2048 bf16 (8 KB)
    unsigned short* sAl = (unsigned short*)(smem + 20480);   // 2 x 2048 bf16 (8 KB)
    const int tid = threadIdx.x;
    const int lane = tid & 63;
    const int w = tid >> 6;
    const int lm = lane & 15, lk = lane >> 4;
    const int row0 = blockIdx.x * 64;
    const int col0 = w * (16 * NFW);

    // staging: wave w stages its 16 rows; lane l -> row l>>2, 8-half chunk l&3.
    // LDS dest linear (= lane*16B) matches convert lane l's read -> no swizzle.
    const int grow = min(row0 + w * 16 + (lane >> 2), N - 1);
    const size_t ga = (size_t)grow * K + (lane & 3) * 8;

    // convert mapping (verified gemm1d/btc layout): write swizzled bf16 chunks.
    const int crow = w * 16 + (lane >> 2);
    const int ch = lane & 3;
    const int cro = (lane >> 2) * 32 + ch * 8;              // linear read offset (halves, within wave seg)
    const int cwo = crow * 32 + (ch ^ (crow & 3)) * 8;      // swizzled write offset (shorts)

    const unsigned short* bfh = Bh + ((size_t)(w * NFW) * NT) * 512 + lane * 8;
    const unsigned short* bfl = Bl + ((size_t)(w * NFW) * NT) * 512 + lane * 8;
    const int aoff = lm * 32 + ((lk ^ (lm & 3)) * 8);

    f32x4 acc[4][NFW];
    #pragma unroll
    for (int i = 0; i < 4; ++i)
        #pragma unroll
        for (int j = 0; j < NFW; ++j) acc[i][j] = (f32x4){0.f, 0.f, 0.f, 0.f};

    auto stage = [&](int bi, int kk) {
        __builtin_amdgcn_global_load_lds((const AS1 void*)(A16 + ga + kk),
                                         (AS3 void*)(sX16 + bi * 2048 + w * 512), 16, 0, 0);
    };

    auto convert = [&](int src, int dst) {
        short8 raw = *(const short8*)(sX16 + src * 2048 + w * 512 + cro);
        short8 ah, al;
        #pragma unroll
        for (int j = 0; j < 8; ++j) {
            _Float16 hv = __builtin_bit_cast(_Float16, (unsigned short)raw[j]);
            float v = (float)hv;
            unsigned int uu = __builtin_bit_cast(unsigned int, v);
            ah[j] = (short)(uu >> 16);
            float hi_ = __builtin_bit_cast(float, uu & 0xFFFF0000u);
            al[j] = (short)f2bf_rne(v - hi_);
        }
        *(short8*)&sAh[dst * 2048 + cwo] = ah;
        *(short8*)&sAl[dst * 2048 + cwo] = al;
    };

    stage(0, 0); stage(1, 32); stage(2, 64);
    short8 bhf[NFW], blf[NFW];
    #pragma unroll
    for (int nf = 0; nf < NFW; ++nf) {
        const size_t o = (size_t)nf * NT * 512;
        bhf[nf] = *(const short8*)(bfh + o);
        blf[nf] = *(const short8*)(bfl + o);
    }
    vm_wait<2 * NFW + 2>();            // drain stage(0)
    convert(0, 0);
    lgkm0();
    __builtin_amdgcn_s_barrier();      // bf16[0] published

    int b0 = 0;

#define GF_BODY(T, VM)                                                          \
    {                                                                           \
        vm_wait<VM>();                                                          \
        __builtin_amdgcn_s_barrier();                                           \
        __builtin_amdgcn_sched_barrier(0);                                      \
        short8 bhn[NFW], bln[NFW];                                              \
        _Pragma("unroll")                                                       \
        for (int nf = 0; nf < NFW; ++nf) { bhn[nf] = bhf[nf]; bln[nf] = blf[nf]; } \
        if ((T) + 1 < NT) {                                                     \
            _Pragma("unroll")                                                   \
            for (int nf = 0; nf < NFW; ++nf) {                                  \
                const size_t o = ((size_t)nf * NT + (T) + 1) * 512;             \
                bhn[nf] = *(const short8*)(bfh + o);                            \
                bln[nf] = *(const short8*)(bfl + o);                            \
            }                                                                   \
        }                                                                       \
        __builtin_amdgcn_sched_barrier(0);                                      \
        _Pragma("unroll")                                                       \
        for (int mf = 0; mf < 4; ++mf) {                                        \
            short8 ah = *(const short8*)&sAh[((T) & 1) * 2048 + aoff + mf * 512]; \
            short8 al = *(const short8*)&sAl[((T) & 1) * 2048 + aoff + mf * 512]; \
            _Pragma("unroll")                                                   \
            for (int nf = 0; nf < NFW; ++nf) {                                  \
                acc[mf][nf] = __builtin_amdgcn_mfma_f32_16x16x32_bf16(ah, bhf[nf], acc[mf][nf], 0, 0, 0); \
                acc[mf][nf] = __builtin_amdgcn_mfma_f32_16x16x32_bf16(ah, blf[nf], acc[mf][nf], 0, 0, 0); \
                acc[mf][nf] = __builtin_amdgcn_mfma_f32_16x16x32_bf16(al, bhf[nf], acc[mf][nf], 0, 0, 0); \
            }                                                                   \
        }                                                                       \
        if ((T) + 1 < NT) {                                                     \
            int src = b0 + 1; if (src == 3) src = 0;                            \
            convert(src, ((T) + 1) & 1);                                        \
        }                                                                       \
        lgkm0();                                                                \
        __builtin_amdgcn_sched_barrier(0);                                      \
        __builtin_amdgcn_s_barrier();                                           \
        if ((T) + 3 < NT) stage(b0, ((T) + 3) * 32);                            \
        _Pragma("unroll")                                                       \
        for (int nf = 0; nf < NFW; ++nf) { bhf[nf] = bhn[nf]; blf[nf] = bln[nf]; } \
        b0 = b0 + 1; if (b0 == 3) b0 = 0;                                       \
    }

    for (int t = 0; t < NT - 2; ++t) GF_BODY(t, 2 * NFW + 1);
    GF_BODY(NT - 2, 2 * NFW);
    GF_BODY(NT - 1, 2 * NFW);
#undef GF_BODY

    float* sc = (float*)smem;
    #pragma unroll
    for (int mf = 0; mf < 4; ++mf) {
        __syncthreads();
        #pragma unroll
        for (int nf = 0; nf < NFW; ++nf)
            #pragma unroll
            for (int r = 0; r < 4; ++r) {
                const int rl = lk * 4 + r;
                const int col = col0 + nf * 16 + lm;
                sc[rl * M + (col ^ (lk << 3))] = acc[mf][nf][r];
            }
        __syncthreads();
        #pragma unroll
        for (int i = 0; i < (16 * UPR) / 256; ++i) {
            const int idx = i * 256 + tid;
            const int rl = idx / UPR, u = idx % UPR;
            const int gr2 = row0 + mf * 16 + rl;
            if (gr2 < N) {
                f32x4 v = *(const f32x4*)&sc[rl * M + ((u * 4) ^ (((rl >> 2) & 3) << 3))];
                half4v h;
                h[0] = (_Float16)v[0]; h[1] = (_Float16)v[1];
                h[2] = (_Float16)v[2]; h[3] = (_Float16)v[3];
                *(half4v*)&Cout[(size_t)gr2 * M + u * 4] = h;
            }
        }
    }
}

// ---------------- SpMM on fp16 input (F=256), wave-per-row, fused bias+relu,
// single fp16 output ----------------
__global__ __launch_bounds__(256)
void k_spmm256f(const int* __restrict__ rp, const int2* __restrict__ ev2,
                const _Float16* __restrict__ in16, const float* __restrict__ bias,
                _Float16* __restrict__ o16, int N) {
    const int lane = threadIdx.x & 63;
    int r = __builtin_amdgcn_readfirstlane(blockIdx.x * 4 + (threadIdx.x >> 6));
    if (r >= N) return;
    const int e0 = __builtin_amdgcn_readfirstlane(rp[r]);
    const int e1 = __builtin_amdgcn_readfirstlane(rp[r + 1]);
    f32x4 acc = {0.f, 0.f, 0.f, 0.f};
    const _Float16* base = in16 + lane * 4;

    #pragma unroll 4
    for (int e = e0; e < e1; ++e) {
        int2 p = ev2[e];
        half4v hv = *(const half4v*)(base + (size_t)p.x * 256);
        float val = __builtin_bit_cast(float, p.y);
        acc[0] = fmaf(val, (float)hv[0], acc[0]);
        acc[1] = fmaf(val, (float)hv[1], acc[1]);
        acc[2] = fmaf(val, (float)hv[2], acc[2]);
        acc[3] = fmaf(val, (float)hv[3], acc[3]);
    }

    f32x4 bv = *(const f32x4*)&bias[lane * 4];
    half4v h;
    #pragma unroll
    for (int j = 0; j < 4; ++j) {
        float o = fmaxf(acc[j] + bv[j], 0.f);
        h[j] = (_Float16)o;
    }
    *(half4v*)&o16[(size_t)r * 256 + lane * 4] = h;
}

// ---------------- SpMM F=128 on fp16 input + fused bias/relu + final dense ----------------
__global__ __launch_bounds__(256)
void k_spmm128f(const int* __restrict__ rp, const int2* __restrict__ ev2,
                const _Float16* __restrict__ in16, const float* __restrict__ b3,
                const float* __restrict__ Wd, const float* __restrict__ bd,
                float* __restrict__ out, int N) {
    __shared__ float Ws[H4 * NCLASS];
    __shared__ float hrow[4][H4];
    {
        int i = threadIdx.x * 8;
        *(f32x4*)&Ws[i] = *(const f32x4*)&Wd[i];
        *(f32x4*)&Ws[i + 4] = *(const f32x4*)&Wd[i + 4];
    }
    __syncthreads();

    const int lane = threadIdx.x & 63;
    const int w = threadIdx.x >> 6;
    int r = __builtin_amdgcn_readfirstlane(blockIdx.x * 4 + w);
    if (r >= N) return;
    const int e0 = __builtin_amdgcn_readfirstlane(rp[r]);
    const int e1 = __builtin_amdgcn_readfirstlane(rp[r + 1]);
    float a0 = 0.f, a1 = 0.f;
    const _Float16* base = in16 + lane * 2;

    #pragma unroll 4
    for (int e = e0; e < e1; ++e) {
        int2 p = ev2[e];
        half2v hv = *(const half2v*)(base + (size_t)p.x * 128);
        float v = __builtin_bit_cast(float, p.y);
        a0 = fmaf(v, (float)hv[0], a0);
        a1 = fmaf(v, (float)hv[1], a1);
    }

    float2 hb;
    hb.x = fmaxf(a0 + b3[lane * 2 + 0], 0.f);
    hb.y = fmaxf(a1 + b3[lane * 2 + 1], 0.f);
    *(float2*)&hrow[w][lane * 2] = hb;

    const int c = lane & 15, q = lane >> 4;
    float s = 0.f;
    #pragma unroll
    for (int k = q * 32; k < q * 32 + 32; ++k)
        s = fmaf(hrow[w][k], Ws[k * NCLASS + c], s);
    s += __shfl_xor(s, 16);
    s += __shfl_xor(s, 32);
    if (lane < 16) out[(size_t)r * NCLASS + lane] = s + bd[lane];
}

extern "C" void kernel_launch(void* const* d_in, const int* in_sizes, int n_in,
                              void* d_out, int out_size, void* d_ws, size_t ws_size,
                              hipStream_t stream) {
    const float* x  = (const float*)d_in[0];
    const int*   er = (const int*)d_in[1];
    const int*   ec = (const int*)d_in[2];
    const float* ev = (const float*)d_in[3];
    const float* W1 = (const float*)d_in[4];
    const float* b1 = (const float*)d_in[5];
    const float* W2 = (const float*)d_in[6];
    const float* b2 = (const float*)d_in[7];
    const float* W3 = (const float*)d_in[8];
    const float* b3 = (const float*)d_in[9];
    const float* Wd = (const float*)d_in[10];
    const float* bd = (const float*)d_in[11];
    float* out = (float*)d_out;

    const int N = in_sizes[0] / NFEAT;
    const int E = in_sizes[1];

    char* w = (char*)d_ws;
    auto alloc = [&](size_t bytes) { char* p = w; w += (bytes + 255) & ~(size_t)255; return p; };
    _Float16* C16 = (_Float16*)alloc((size_t)N * 256 * 2);
    _Float16* h16 = (_Float16*)alloc((size_t)N * 256 * 2);
    int* cnt  = (int*)alloc((size_t)N * 4);
    int* rp   = (int*)alloc((size_t)(N + 1) * 4);
    int* ofs  = (int*)alloc((size_t)N * 4);
    int2* ev2 = (int2*)alloc((size_t)E * 8);
    int* bsum = (int*)alloc(4096);
    unsigned short* W1h = (unsigned short*)alloc((size_t)NFEAT * H2 * 2);
    unsigned short* W1l = (unsigned short*)alloc((size_t)NFEAT * H2 * 2);
    unsigned short* W2h = (unsigned short*)alloc((size_t)H2 * H3 * 2);
    unsigned short* W2l = (unsigned short*)alloc((size_t)H2 * H3 * 2);
    unsigned short* W3h = (unsigned short*)alloc((size_t)H3 * H4 * 2);
    unsigned short* W3l = (unsigned short*)alloc((size_t)H3 * H4 * 2);

    const int nb = (N + 255) / 256;
    const int sliceSz = (N + 7) / 8;

    hipMemsetAsync(cnt, 0, (size_t)N * 4, stream);
    k_hist<<<1024, 256, 0, stream>>>(er, cnt, E);
    k_scan1<<<nb, 256, 0, stream>>>(cnt, rp, bsum, N);
    k_scan2<<<1, 512, 0, stream>>>(bsum, nb);
    k_scan3<<<nb, 256, 0, stream>>>(rp, ofs, bsum, cnt, N);
    k_scatter_sl<<<2048, 256, 0, stream>>>(er, ec, ev, ofs, ev2, E, sliceSz);

    k_packb<<<(NFEAT * H2 / 8 + 255) / 256, 256, 0, stream>>>(W1, W1h, W1l, NFEAT, H2);
    k_packb<<<(H2 * H3 / 8 + 255) / 256, 256, 0, stream>>>(W2, W2h, W2l, H2, H3);
    k_packb<<<(H3 * H4 / 8 + 255) / 256, 256, 0, stream>>>(W3, W3h, W3l, H3, H4);

    const int rgrid = (N + 63) / 64;
    const int sgrid = (N + 3) / 4;

    k_gemm1d<<<rgrid, 256, 0, stream>>>(x, W1h, W1l, C16, N);
    k_spmm256f<<<sgrid, 256, 0, stream>>>(rp, ev2, C16, b1, h16, N);

    k_gemm_f16a<H2, 4><<<rgrid, 256, 0, stream>>>(h16, W2h, W2l, C16, N);
    k_spmm256f<<<sgrid, 256, 0, stream>>>(rp, ev2, C16, b2, h16, N);

    k_gemm_f16a<H3, 2><<<rgrid, 256, 0, stream>>>(h16, W3h, W3l, C16, N);
    k_spmm128f<<<sgrid, 256, 0, stream>>>(rp, ev2, C16, b3, Wd, bd, out, N);
}

// Round 23
// 614.924 us; speedup vs baseline: 1.0838x; 1.0572x over previous
//
#include <hip/hip_runtime.h>
#include <hip/hip_bf16.h>
#include <cstdint>
#include <cstddef>

#define NFEAT 512
#define H2 256
#define H3 256
#define H4 128
#define NCLASS 16

typedef __attribute__((ext_vector_type(8))) short short8;
typedef __attribute__((ext_vector_type(4))) float f32x4;
typedef __attribute__((ext_vector_type(4))) unsigned short ushort4v;
typedef __attribute__((ext_vector_type(8))) _Float16 half8v;
typedef __attribute__((ext_vector_type(4))) _Float16 half4v;
typedef __attribute__((ext_vector_type(2))) _Float16 half2v;

#define AS1 __attribute__((address_space(1)))
#define AS3 __attribute__((address_space(3)))

__device__ inline unsigned short f2bf_rne(float x) {
    unsigned int u = __builtin_bit_cast(unsigned int, x);
    unsigned int r = (u + 0x7FFFu + ((u >> 16) & 1u)) >> 16;
    return (unsigned short)r;
}
__device__ inline float bf2f(unsigned short h) {
    return __builtin_bit_cast(float, (unsigned int)h << 16);
}

template <int VM> __device__ __forceinline__ void vm_wait() {
    asm volatile("s_waitcnt vmcnt(%0)" :: "n"(VM) : "memory");
}
__device__ __forceinline__ void lgkm0() {
    asm volatile("s_waitcnt lgkmcnt(0)" ::: "memory");
}

// ---------------- CSR build ----------------
__global__ void k_hist(const int* __restrict__ er, int* __restrict__ cnt, int E) {
    for (int e = blockIdx.x * blockDim.x + threadIdx.x; e < E; e += gridDim.x * blockDim.x)
        atomicAdd(&cnt[er[e]], 1);
}

__global__ void k_scan1(const int* __restrict__ cnt, int* __restrict__ ex,
                        int* __restrict__ bsum, int n) {
    __shared__ int s[256];
    int i = blockIdx.x * 256 + threadIdx.x;
    int v = (i < n) ? cnt[i] : 0;
    s[threadIdx.x] = v;
    __syncthreads();
    #pragma unroll
    for (int off = 1; off < 256; off <<= 1) {
        int t = (threadIdx.x >= (unsigned)off) ? s[threadIdx.x - off] : 0;
        __syncthreads();
        s[threadIdx.x] += t;
        __syncthreads();
    }
    if (i < n) ex[i] = s[threadIdx.x] - v;
    if (threadIdx.x == 255) bsum[blockIdx.x] = s[255];
}

__global__ void k_scan2(int* __restrict__ bsum, int nb) {
    __shared__ int s[512];
    int v = ((int)threadIdx.x < nb) ? bsum[threadIdx.x] : 0;
    s[threadIdx.x] = v;
    __syncthreads();
    #pragma unroll
    for (int off = 1; off < 512; off <<= 1) {
        int t = (threadIdx.x >= (unsigned)off) ? s[threadIdx.x - off] : 0;
        __syncthreads();
        s[threadIdx.x] += t;
        __syncthreads();
    }
    if ((int)threadIdx.x < nb) bsum[threadIdx.x] = s[threadIdx.x] - v;
}

__global__ void k_scan3(int* __restrict__ rp, int* __restrict__ ofs,
                        const int* __restrict__ bsum, const int* __restrict__ cnt,
                        int n) {
    int i = blockIdx.x * 256 + threadIdx.x;
    if (i < n) {
        int v = rp[i] + bsum[blockIdx.x];
        rp[i] = v;
        ofs[i] = v;
        if (i == n - 1) rp[n] = v + cnt[i];
    }
}

// sliced scatter: slice s commits only rows in its N/8 window.
__global__ void k_scatter_sl(const int* __restrict__ er, const int* __restrict__ ec,
                             const float* __restrict__ ev, int* __restrict__ ofs,
                             int2* __restrict__ ev2, int E, int sliceSz) {
    const int slice = blockIdx.x & 7;
    const int g = blockIdx.x >> 3;
    const int rlo = slice * sliceSz;
    const int rhi = rlo + sliceSz;
    for (int e = g * 256 + threadIdx.x; e < E; e += 256 * 256) {
        int r = er[e];
        if (r >= rlo && r < rhi) {
            int p = atomicAdd(&ofs[r], 1);
            ev2[p] = make_int2(ec[e], __builtin_bit_cast(int, ev[e]));
        }
    }
}

// ---------------- weight pack: W[K][M] fp32 -> fragment-major bf16 hi/lo (layer 1) ----------------
__global__ __launch_bounds__(256)
void k_packb(const float* __restrict__ W, unsigned short* __restrict__ hi,
             unsigned short* __restrict__ lo, int K, int M) {
    int idx = blockIdx.x * 256 + threadIdx.x;
    int NT = K >> 5;
    int total = (M >> 4) * NT * 64;
    if (idx >= total) return;
    int l = idx & 63;
    int t = (idx >> 6) % NT;
    int cg = idx / (NT << 6);
    int col = cg * 16 + (l & 15);
    int k0 = t * 32 + (l >> 4) * 8;
    short8 h8, l8;
    #pragma unroll
    for (int j = 0; j < 8; ++j) {
        float x = W[(size_t)(k0 + j) * M + col];
        unsigned short h = f2bf_rne(x);
        h8[j] = (short)h;
        l8[j] = (short)f2bf_rne(x - bf2f(h));
    }
    *(short8*)&hi[(size_t)idx * 8] = h8;
    *(short8*)&lo[(size_t)idx * 8] = l8;
}

// ---------------- weight pack fp16: W[K][M] fp32 -> fragment-major fp16 hi/lo ----------------
__global__ __launch_bounds__(256)
void k_packb16(const float* __restrict__ W, _Float16* __restrict__ hi,
               _Float16* __restrict__ lo, int K, int M) {
    int idx = blockIdx.x * 256 + threadIdx.x;
    int NT = K >> 5;
    int total = (M >> 4) * NT * 64;
    if (idx >= total) return;
    int l = idx & 63;
    int t = (idx >> 6) % NT;
    int cg = idx / (NT << 6);
    int col = cg * 16 + (l & 15);
    int k0 = t * 32 + (l >> 4) * 8;
    half8v h8, l8;
    #pragma unroll
    for (int j = 0; j < 8; ++j) {
        float x = W[(size_t)(k0 + j) * M + col];
        _Float16 h = (_Float16)x;
        h8[j] = h;
        l8[j] = (_Float16)(x - (float)h);
    }
    *(half8v*)&hi[(size_t)idx * 8] = h8;
    *(half8v*)&lo[(size_t)idx * 8] = l8;
}

// ---------------- GEMM1 (counted-vmcnt, 3 fp32 bufs, cooperative convert to
// 2 bf16 dbuf): C16[N,256] = fp16(X[N,512] @ W1). Each element converted ONCE.
__global__ __launch_bounds__(256, 3)
void k_gemm1d(const float* __restrict__ X, const unsigned short* __restrict__ Bh,
              const unsigned short* __restrict__ Bl, _Float16* __restrict__ C16, const int N) {
    constexpr int K = 512, M = 256, NT = K / 32;
    __shared__ char smem[40960];
    float* sXf = (float*)smem;
    unsigned short* sAh = (unsigned short*)(smem + 24576);
    unsigned short* sAl = (unsigned short*)(smem + 32768);
    const int tid = threadIdx.x;
    const int lane = tid & 63;
    const int w = tid >> 6;
    const int lm = lane & 15, lk = lane >> 4;
    const int row0 = blockIdx.x * 64;
    const int col0 = w * 64;

    const int kseg = (lane & 7) ^ ((lane >> 3) & 7);
    const int r0 = min(row0 + w * 16 + (lane >> 3), N - 1);
    const int r1 = min(row0 + w * 16 + 8 + (lane >> 3), N - 1);
    const size_t ga0 = (size_t)r0 * K + kseg * 4;
    const size_t ga1 = (size_t)r1 * K + kseg * 4;

    const int crow = w * 16 + (lane >> 2);
    const int ch = lane & 3;
    const int cu0 = ((2 * ch) ^ (crow & 7)) * 4;
    const int cu1 = ((2 * ch + 1) ^ (crow & 7)) * 4;
    const int cwo = crow * 32 + (ch ^ (crow & 3)) * 8;

    const unsigned short* bfh = Bh + ((size_t)(w * 4) * NT) * 512 + lane * 8;
    const unsigned short* bfl = Bl + ((size_t)(w * 4) * NT) * 512 + lane * 8;
    const int aoff = lm * 32 + ((lk ^ (lm & 3)) * 8);

    f32x4 acc[4][4];
    #pragma unroll
    for (int i = 0; i < 4; ++i)
        #pragma unroll
        for (int j = 0; j < 4; ++j) acc[i][j] = (f32x4){0.f, 0.f, 0.f, 0.f};

    auto stage = [&](int bi, int kk) {
        __builtin_amdgcn_global_load_lds((const AS1 void*)(X + ga0 + kk),
                                         (AS3 void*)(sXf + bi * 2048 + w * 512), 16, 0, 0);
        __builtin_amdgcn_global_load_lds((const AS1 void*)(X + ga1 + kk),
                                         (AS3 void*)(sXf + bi * 2048 + w * 512 + 256), 16, 0, 0);
    };

    auto convert = [&](int src, int dst) {
        const float* s = sXf + src * 2048 + crow * 32;
        f32x4 p0 = *(const f32x4*)(s + cu0);
        f32x4 p1 = *(const f32x4*)(s + cu1);
        float vv[8] = {p0.x, p0.y, p0.z, p0.w, p1.x, p1.y, p1.z, p1.w};
        short8 ah, al;
        #pragma unroll
        for (int j = 0; j < 8; ++j) {
            unsigned int uu = __builtin_bit_cast(unsigned int, vv[j]);
            ah[j] = (short)(uu >> 16);
            float hi_ = __builtin_bit_cast(float, uu & 0xFFFF0000u);
            al[j] = (short)f2bf_rne(vv[j] - hi_);
        }
        *(short8*)&sAh[dst * 2048 + cwo] = ah;
        *(short8*)&sAl[dst * 2048 + cwo] = al;
    };

    stage(0, 0); stage(1, 32); stage(2, 64);
    short8 bhf[4], blf[4];
    #pragma unroll
    for (int nf = 0; nf < 4; ++nf) {
        const size_t o = (size_t)nf * NT * 512;
        bhf[nf] = *(const short8*)(bfh + o);
        blf[nf] = *(const short8*)(bfl + o);
    }
    vm_wait<12>();
    convert(0, 0);
    lgkm0();
    __builtin_amdgcn_s_barrier();

    int b0 = 0;

#define G1D_BODY(T, VM)                                                         \
    {                                                                           \
        vm_wait<VM>();                                                          \
        __builtin_amdgcn_s_barrier();                                           \
        __builtin_amdgcn_sched_barrier(0);                                      \
        short8 bhn[4], bln[4];                                                  \
        _Pragma("unroll")                                                       \
        for (int nf = 0; nf < 4; ++nf) { bhn[nf] = bhf[nf]; bln[nf] = blf[nf]; }\
        if ((T) + 1 < NT) {                                                     \
            _Pragma("unroll")                                                   \
            for (int nf = 0; nf < 4; ++nf) {                                    \
                const size_t o = ((size_t)nf * NT + (T) + 1) * 512;             \
                bhn[nf] = *(const short8*)(bfh + o);                            \
                bln[nf] = *(const short8*)(bfl + o);                            \
            }                                                                   \
        }                                                                       \
        __builtin_amdgcn_sched_barrier(0);                                      \
        _Pragma("unroll")                                                       \
        for (int mf = 0; mf < 4; ++mf) {                                        \
            short8 ah = *(const short8*)&sAh[((T) & 1) * 2048 + aoff + mf * 512]; \
            short8 al = *(const short8*)&sAl[((T) & 1) * 2048 + aoff + mf * 512]; \
            _Pragma("unroll")                                                   \
            for (int nf = 0; nf < 4; ++nf) {                                    \
                acc[mf][nf] = __builtin_amdgcn_mfma_f32_16x16x32_bf16(ah, bhf[nf], acc[mf][nf], 0, 0, 0); \
                acc[mf][nf] = __builtin_amdgcn_mfma_f32_16x16x32_bf16(ah, blf[nf], acc[mf][nf], 0, 0, 0); \
                acc[mf][nf] = __builtin_amdgcn_mfma_f32_16x16x32_bf16(al, bhf[nf], acc[mf][nf], 0, 0, 0); \
            }                                                                   \
        }                                                                       \
        if ((T) + 1 < NT) {                                                     \
            int src = b0 + 1; if (src == 3) src = 0;                            \
            convert(src, ((T) + 1) & 1);                                        \
        }                                                                       \
        lgkm0();                                                                \
        __builtin_amdgcn_sched_barrier(0);                                      \
        __builtin_amdgcn_s_barrier();                                           \
        if ((T) + 3 < NT) stage(b0, ((T) + 3) * 32);                            \
        _Pragma("unroll")                                                       \
        for (int nf = 0; nf < 4; ++nf) { bhf[nf] = bhn[nf]; blf[nf] = bln[nf]; }\
        b0 = b0 + 1; if (b0 == 3) b0 = 0;                                       \
    }

    for (int t = 0; t < NT - 2; ++t) G1D_BODY(t, 10);
    G1D_BODY(NT - 2, 8);
    G1D_BODY(NT - 1, 8);
#undef G1D_BODY

    float* sc = (float*)smem;
    #pragma unroll
    for (int mf = 0; mf < 4; ++mf) {
        __syncthreads();
        #pragma unroll
        for (int nf = 0; nf < 4; ++nf)
            #pragma unroll
            for (int r = 0; r < 4; ++r) {
                const int rl = lk * 4 + r;
                const int col = col0 + nf * 16 + lm;
                sc[rl * M + (col ^ (lk << 3))] = acc[mf][nf][r];
            }
        __syncthreads();
        #pragma unroll
        for (int i = 0; i < 4; ++i) {
            const int idx = i * 256 + tid;
            const int rl = idx >> 6, u = idx & 63;
            const int grow = row0 + mf * 16 + rl;
            if (grow < N) {
                f32x4 v = *(const f32x4*)&sc[rl * M + ((u * 4) ^ (((rl >> 2) & 3) << 3))];
                half4v h;
                h[0] = (_Float16)v[0]; h[1] = (_Float16)v[1];
                h[2] = (_Float16)v[2]; h[3] = (_Float16)v[3];
                *(half4v*)&C16[(size_t)grow * M + u * 4] = h;
            }
        }
    }
}

// ---------------- GEMM fp16-MFMA (A exact fp16, B fp16 hi/lo, 2 MFMA passes,
// NO convert phase). counted-vmcnt, 3 fp16 A bufs. ----------------
template <int K, int NFW>
__global__ __launch_bounds__(256, 3)
void k_gemm_f16b(const _Float16* __restrict__ A16, const _Float16* __restrict__ Bh,
                 const _Float16* __restrict__ Bl, _Float16* __restrict__ Cout,
                 const int N) {
    constexpr int M = 64 * NFW;
    constexpr int NT = K / 32;
    constexpr int UPR = 16 * NFW;
    __shared__ char smem[16384];                 // 3 x 2048 halves (12 KB); epilogue 16*M*4 <= 16 KB
    _Float16* sX = (_Float16*)smem;
    const int tid = threadIdx.x;
    const int lane = tid & 63;
    const int w = tid >> 6;
    const int lm = lane & 15, lk = lane >> 4;
    const int row0 = blockIdx.x * 64;
    const int col0 = w * (16 * NFW);

    // staging with pre-swizzled global kseg (gemm_btc-proven pattern)
    const int kseg = (lane & 3) ^ ((lane >> 2) & 3);
    const int gr = min(row0 + w * 16 + (lane >> 2), N - 1);
    const size_t ga = (size_t)gr * K + kseg * 8;

    const int aoff = lm * 32 + ((lk ^ (lm & 3)) * 8);

    const _Float16* bfh = Bh + ((size_t)(w * NFW) * NT) * 512 + lane * 8;
    const _Float16* bfl = Bl + ((size_t)(w * NFW) * NT) * 512 + lane * 8;

    f32x4 acc[4][NFW];
    #pragma unroll
    for (int i = 0; i < 4; ++i)
        #pragma unroll
        for (int j = 0; j < NFW; ++j) acc[i][j] = (f32x4){0.f, 0.f, 0.f, 0.f};

    auto stage = [&](int bi, int kk) {
        __builtin_amdgcn_global_load_lds((const AS1 void*)(A16 + ga + kk),
                                         (AS3 void*)(sX + bi * 2048 + w * 512), 16, 0, 0);
    };

    stage(0, 0); stage(1, 32); stage(2, 64);

    half8v bhf[NFW], blf[NFW];
    #pragma unroll
    for (int nf = 0; nf < NFW; ++nf) {
        const size_t o = (size_t)nf * NT * 512;
        bhf[nf] = *(const half8v*)(bfh + o);
        blf[nf] = *(const half8v*)(bfl + o);
    }

    int bi = 0;

#define GF16_BODY(T, VM)                                                        \
    {                                                                           \
        vm_wait<VM>();                                                          \
        __builtin_amdgcn_s_barrier();                                           \
        __builtin_amdgcn_sched_barrier(0);                                      \
        half8v bhn[NFW], bln[NFW];                                              \
        _Pragma("unroll")                                                       \
        for (int nf = 0; nf < NFW; ++nf) { bhn[nf] = bhf[nf]; bln[nf] = blf[nf]; } \
        if ((T) + 1 < NT) {                                                     \
            _Pragma("unroll")                                                   \
            for (int nf = 0; nf < NFW; ++nf) {                                  \
                const size_t o = ((size_t)nf * NT + (T) + 1) * 512;             \
                bhn[nf] = *(const half8v*)(bfh + o);                            \
                bln[nf] = *(const half8v*)(bfl + o);                            \
            }                                                                   \
        }                                                                       \
        __builtin_amdgcn_sched_barrier(0);                                      \
        _Pragma("unroll")                                                       \
        for (int mf = 0; mf < 4; ++mf) {                                        \
            half8v av = *(const half8v*)&sX[bi * 2048 + aoff + mf * 512];       \
            _Pragma("unroll")                                                   \
            for (int nf = 0; nf < NFW; ++nf) {                                  \
                acc[mf][nf] = __builtin_amdgcn_mfma_f32_16x16x32_f16(av, bhf[nf], acc[mf][nf], 0, 0, 0); \
                acc[mf][nf] = __builtin_amdgcn_mfma_f32_16x16x32_f16(av, blf[nf], acc[mf][nf], 0, 0, 0); \
            }                                                                   \
        }                                                                       \
        lgkm0();                                                                \
        __builtin_amdgcn_sched_barrier(0);                                      \
        __builtin_amdgcn_s_barrier();                                           \
        if ((T) + 3 < NT) stage(bi, ((T) + 3) * 32);                            \
        _Pragma("unroll")                                                       \
        for (int nf = 0; nf < NFW; ++nf) { bhf[nf] = bhn[nf]; blf[nf] = bln[nf]; } \
        bi = bi + 1; if (bi == 3) bi = 0;                                       \
    }

    for (int t = 0; t < NT - 2; ++t) GF16_BODY(t, 2 * NFW + 2);
    GF16_BODY(NT - 2, 2 * NFW + 1);
    GF16_BODY(NT - 1, 2 * NFW);
#undef GF16_BODY

    float* sc = (float*)smem;
    #pragma unroll
    for (int mf = 0; mf < 4; ++mf) {
        __syncthreads();
        #pragma unroll
        for (int nf = 0; nf < NFW; ++nf)
            #pragma unroll
            for (int r = 0; r < 4; ++r) {
                const int rl = lk * 4 + r;
                const int col = col0 + nf * 16 + lm;
                sc[rl * M + (col ^ (lk << 3))] = acc[mf][nf][r];
            }
        __syncthreads();
        #pragma unroll
        for (int i = 0; i < (16 * UPR) / 256; ++i) {
            const int idx = i * 256 + tid;
            const int rl = idx / UPR, u = idx % UPR;
            const int gr2 = row0 + mf * 16 + rl;
            if (gr2 < N) {
                f32x4 v = *(const f32x4*)&sc[rl * M + ((u * 4) ^ (((rl >> 2) & 3) << 3))];
                half4v h;
                h[0] = (_Float16)v[0]; h[1] = (_Float16)v[1];
                h[2] = (_Float16)v[2]; h[3] = (_Float16)v[3];
                *(half4v*)&Cout[(size_t)gr2 * M + u * 4] = h;
            }
        }
    }
}

// ---------------- SpMM on fp16 input (F=256), wave-per-row, fused bias+relu,
// single fp16 output ----------------
__global__ __launch_bounds__(256)
void k_spmm256f(const int* __restrict__ rp, const int2* __restrict__ ev2,
                const _Float16* __restrict__ in16, const float* __restrict__ bias,
                _Float16* __restrict__ o16, int N) {
    const int lane = threadIdx.x & 63;
    int r = __builtin_amdgcn_readfirstlane(blockIdx.x * 4 + (threadIdx.x >> 6));
    if (r >= N) return;
    const int e0 = __builtin_amdgcn_readfirstlane(rp[r]);
    const int e1 = __builtin_amdgcn_readfirstlane(rp[r + 1]);
    f32x4 acc = {0.f, 0.f, 0.f, 0.f};
    const _Float16* base = in16 + lane * 4;

    #pragma unroll 4
    for (int e = e0; e < e1; ++e) {
        int2 p = ev2[e];
        half4v hv = *(const half4v*)(base + (size_t)p.x * 256);
        float val = __builtin_bit_cast(float, p.y);
        acc[0] = fmaf(val, (float)hv[0], acc[0]);
        acc[1] = fmaf(val, (float)hv[1], acc[1]);
        acc[2] = fmaf(val, (float)hv[2], acc[2]);
        acc[3] = fmaf(val, (float)hv[3], acc[3]);
    }

    f32x4 bv = *(const f32x4*)&bias[lane * 4];
    half4v h;
    #pragma unroll
    for (int j = 0; j < 4; ++j) {
        float o = fmaxf(acc[j] + bv[j], 0.f);
        h[j] = (_Float16)o;
    }
    *(half4v*)&o16[(size_t)r * 256 + lane * 4] = h;
}

// ---------------- SpMM F=128 on fp16 input + fused bias/relu + final dense ----------------
__global__ __launch_bounds__(256)
void k_spmm128f(const int* __restrict__ rp, const int2* __restrict__ ev2,
                const _Float16* __restrict__ in16, const float* __restrict__ b3,
                const float* __restrict__ Wd, const float* __restrict__ bd,
                float* __restrict__ out, int N) {
    __shared__ float Ws[H4 * NCLASS];
    __shared__ float hrow[4][H4];
    {
        int i = threadIdx.x * 8;
        *(f32x4*)&Ws[i] = *(const f32x4*)&Wd[i];
        *(f32x4*)&Ws[i + 4] = *(const f32x4*)&Wd[i + 4];
    }
    __syncthreads();

    const int lane = threadIdx.x & 63;
    const int w = threadIdx.x >> 6;
    int r = __builtin_amdgcn_readfirstlane(blockIdx.x * 4 + w);
    if (r >= N) return;
    const int e0 = __builtin_amdgcn_readfirstlane(rp[r]);
    const int e1 = __builtin_amdgcn_readfirstlane(rp[r + 1]);
    float a0 = 0.f, a1 = 0.f;
    const _Float16* base = in16 + lane * 2;

    #pragma unroll 4
    for (int e = e0; e < e1; ++e) {
        int2 p = ev2[e];
        half2v hv = *(const half2v*)(base + (size_t)p.x * 128);
        float v = __builtin_bit_cast(float, p.y);
        a0 = fmaf(v, (float)hv[0], a0);
        a1 = fmaf(v, (float)hv[1], a1);
    }

    float2 hb;
    hb.x = fmaxf(a0 + b3[lane * 2 + 0], 0.f);
    hb.y = fmaxf(a1 + b3[lane * 2 + 1], 0.f);
    *(float2*)&hrow[w][lane * 2] = hb;

    const int c = lane & 15, q = lane >> 4;
    float s = 0.f;
    #pragma unroll
    for (int k = q * 32; k < q * 32 + 32; ++k)
        s = fmaf(hrow[w][k], Ws[k * NCLASS + c], s);
    s += __shfl_xor(s, 16);
    s += __shfl_xor(s, 32);
    if (lane < 16) out[(size_t)r * NCLASS + lane] = s + bd[lane];
}

extern "C" void kernel_launch(void* const* d_in, const int* in_sizes, int n_in,
                              void* d_out, int out_size, void* d_ws, size_t ws_size,
                              hipStream_t stream) {
    const float* x  = (const float*)d_in[0];
    const int*   er = (const int*)d_in[1];
    const int*   ec = (const int*)d_in[2];
    const float* ev = (const float*)d_in[3];
    const float* W1 = (const float*)d_in[4];
    const float* b1 = (const float*)d_in[5];
    const float* W2 = (const float*)d_in[6];
    const float* b2 = (const float*)d_in[7];
    const float* W3 = (const float*)d_in[8];
    const float* b3 = (const float*)d_in[9];
    const float* Wd = (const float*)d_in[10];
    const float* bd = (const float*)d_in[11];
    float* out = (float*)d_out;

    const int N = in_sizes[0] / NFEAT;
    const int E = in_sizes[1];

    char* w = (char*)d_ws;
    auto alloc = [&](size_t bytes) { char* p = w; w += (bytes + 255) & ~(size_t)255; return p; };
    _Float16* C16 = (_Float16*)alloc((size_t)N * 256 * 2);
    _Float16* h16 = (_Float16*)alloc((size_t)N * 256 * 2);
    int* cnt  = (int*)alloc((size_t)N * 4);
    int* rp   = (int*)alloc((size_t)(N + 1) * 4);
    int* ofs  = (int*)alloc((size_t)N * 4);
    int2* ev2 = (int2*)alloc((size_t)E * 8);
    int* bsum = (int*)alloc(4096);
    unsigned short* W1h = (unsigned short*)alloc((size_t)NFEAT * H2 * 2);
    unsigned short* W1l = (unsigned short*)alloc((size_t)NFEAT * H2 * 2);
    _Float16* W2h = (_Float16*)alloc((size_t)H2 * H3 * 2);
    _Float16* W2l = (_Float16*)alloc((size_t)H2 * H3 * 2);
    _Float16* W3h = (_Float16*)alloc((size_t)H3 * H4 * 2);
    _Float16* W3l = (_Float16*)alloc((size_t)H3 * H4 * 2);

    const int nb = (N + 255) / 256;
    const int sliceSz = (N + 7) / 8;

    hipMemsetAsync(cnt, 0, (size_t)N * 4, stream);
    k_hist<<<1024, 256, 0, stream>>>(er, cnt, E);
    k_scan1<<<nb, 256, 0, stream>>>(cnt, rp, bsum, N);
    k_scan2<<<1, 512, 0, stream>>>(bsum, nb);
    k_scan3<<<nb, 256, 0, stream>>>(rp, ofs, bsum, cnt, N);
    k_scatter_sl<<<2048, 256, 0, stream>>>(er, ec, ev, ofs, ev2, E, sliceSz);

    k_packb<<<(NFEAT * H2 / 8 + 255) / 256, 256, 0, stream>>>(W1, W1h, W1l, NFEAT, H2);
    k_packb16<<<(H2 * H3 / 8 + 255) / 256, 256, 0, stream>>>(W2, W2h, W2l, H2, H3);
    k_packb16<<<(H3 * H4 / 8 + 255) / 256, 256, 0, stream>>>(W3, W3h, W3l, H3, H4);

    const int rgrid = (N + 63) / 64;
    const int sgrid = (N + 3) / 4;

    k_gemm1d<<<rgrid, 256, 0, stream>>>(x, W1h, W1l, C16, N);
    k_spmm256f<<<sgrid, 256, 0, stream>>>(rp, ev2, C16, b1, h16, N);

    k_gemm_f16b<H2, 4><<<rgrid, 256, 0, stream>>>(h16, W2h, W2l, C16, N);
    k_spmm256f<<<sgrid, 256, 0, stream>>>(rp, ev2, C16, b2, h16, N);

    k_gemm_f16b<H3, 2><<<rgrid, 256, 0, stream>>>(h16, W3h, W3l, C16, N);
    k_spmm128f<<<sgrid, 256, 0, stream>>>(rp, ev2, C16, b3, Wd, bd, out, N);
}

// Round 25
// 611.958 us; speedup vs baseline: 1.0891x; 1.0048x over previous
//
#include <hip/hip_runtime.h>
#include <hip/hip_bf16.h>
#include <cstdint>
#include <cstddef>

#define NFEAT 512
#define H2 256
#define H3 256
#define H4 128
#define NCLASS 16

typedef __attribute__((ext_vector_type(8))) short short8;
typedef __attribute__((ext_vector_type(4))) float f32x4;
typedef __attribute__((ext_vector_type(4))) unsigned short ushort4v;
typedef __attribute__((ext_vector_type(8))) _Float16 half8v;
typedef __attribute__((ext_vector_type(4))) _Float16 half4v;
typedef __attribute__((ext_vector_type(2))) _Float16 half2v;

#define AS1 __attribute__((address_space(1)))
#define AS3 __attribute__((address_space(3)))

__device__ inline unsigned short f2bf_rne(float x) {
    unsigned int u = __builtin_bit_cast(unsigned int, x);
    unsigned int r = (u + 0x7FFFu + ((u >> 16) & 1u)) >> 16;
    return (unsigned short)r;
}
__device__ inline float bf2f(unsigned short h) {
    return __builtin_bit_cast(float, (unsigned int)h << 16);
}

template <int VM> __device__ __forceinline__ void vm_wait() {
    asm volatile("s_waitcnt vmcnt(%0)" :: "n"(VM) : "memory");
}
__device__ __forceinline__ void lgkm0() {
    asm volatile("s_waitcnt lgkmcnt(0)" ::: "memory");
}

// ---------------- CSR build ----------------
__global__ void k_hist(const int* __restrict__ er, int* __restrict__ cnt, int E) {
    for (int e = blockIdx.x * blockDim.x + threadIdx.x; e < E; e += gridDim.x * blockDim.x)
        atomicAdd(&cnt[er[e]], 1);
}

__global__ void k_scan1(const int* __restrict__ cnt, int* __restrict__ ex,
                        int* __restrict__ bsum, int n) {
    __shared__ int s[256];
    int i = blockIdx.x * 256 + threadIdx.x;
    int v = (i < n) ? cnt[i] : 0;
    s[threadIdx.x] = v;
    __syncthreads();
    #pragma unroll
    for (int off = 1; off < 256; off <<= 1) {
        int t = (threadIdx.x >= (unsigned)off) ? s[threadIdx.x - off] : 0;
        __syncthreads();
        s[threadIdx.x] += t;
        __syncthreads();
    }
    if (i < n) ex[i] = s[threadIdx.x] - v;
    if (threadIdx.x == 255) bsum[blockIdx.x] = s[255];
}

__global__ void k_scan2(int* __restrict__ bsum, int nb) {
    __shared__ int s[512];
    int v = ((int)threadIdx.x < nb) ? bsum[threadIdx.x] : 0;
    s[threadIdx.x] = v;
    __syncthreads();
    #pragma unroll
    for (int off = 1; off < 512; off <<= 1) {
        int t = (threadIdx.x >= (unsigned)off) ? s[threadIdx.x - off] : 0;
        __syncthreads();
        s[threadIdx.x] += t;
        __syncthreads();
    }
    if ((int)threadIdx.x < nb) bsum[threadIdx.x] = s[threadIdx.x] - v;
}

__global__ void k_scan3(int* __restrict__ rp, int* __restrict__ ofs,
                        const int* __restrict__ bsum, const int* __restrict__ cnt,
                        int n) {
    int i = blockIdx.x * 256 + threadIdx.x;
    if (i < n) {
        int v = rp[i] + bsum[blockIdx.x];
        rp[i] = v;
        ofs[i] = v;
        if (i == n - 1) rp[n] = v + cnt[i];
    }
}

// sliced scatter: slice s commits only rows in its N/8 window.
__global__ void k_scatter_sl(const int* __restrict__ er, const int* __restrict__ ec,
                             const float* __restrict__ ev, int* __restrict__ ofs,
                             int2* __restrict__ ev2, int E, int sliceSz) {
    const int slice = blockIdx.x & 7;
    const int g = blockIdx.x >> 3;
    const int rlo = slice * sliceSz;
    const int rhi = rlo + sliceSz;
    for (int e = g * 256 + threadIdx.x; e < E; e += 256 * 256) {
        int r = er[e];
        if (r >= rlo && r < rhi) {
            int p = atomicAdd(&ofs[r], 1);
            ev2[p] = make_int2(ec[e], __builtin_bit_cast(int, ev[e]));
        }
    }
}

// ---------------- weight pack: W[K][M] fp32 -> fragment-major bf16 hi/lo (layer 1) ----------------
__global__ __launch_bounds__(256)
void k_packb(const float* __restrict__ W, unsigned short* __restrict__ hi,
             unsigned short* __restrict__ lo, int K, int M) {
    int idx = blockIdx.x * 256 + threadIdx.x;
    int NT = K >> 5;
    int total = (M >> 4) * NT * 64;
    if (idx >= total) return;
    int l = idx & 63;
    int t = (idx >> 6) % NT;
    int cg = idx / (NT << 6);
    int col = cg * 16 + (l & 15);
    int k0 = t * 32 + (l >> 4) * 8;
    short8 h8, l8;
    #pragma unroll
    for (int j = 0; j < 8; ++j) {
        float x = W[(size_t)(k0 + j) * M + col];
        unsigned short h = f2bf_rne(x);
        h8[j] = (short)h;
        l8[j] = (short)f2bf_rne(x - bf2f(h));
    }
    *(short8*)&hi[(size_t)idx * 8] = h8;
    *(short8*)&lo[(size_t)idx * 8] = l8;
}

// ---------------- weight pack fp16: W[K][M] fp32 -> fragment-major fp16 hi/lo ----------------
__global__ __launch_bounds__(256)
void k_packb16(const float* __restrict__ W, _Float16* __restrict__ hi,
               _Float16* __restrict__ lo, int K, int M) {
    int idx = blockIdx.x * 256 + threadIdx.x;
    int NT = K >> 5;
    int total = (M >> 4) * NT * 64;
    if (idx >= total) return;
    int l = idx & 63;
    int t = (idx >> 6) % NT;
    int cg = idx / (NT << 6);
    int col = cg * 16 + (l & 15);
    int k0 = t * 32 + (l >> 4) * 8;
    half8v h8, l8;
    #pragma unroll
    for (int j = 0; j < 8; ++j) {
        float x = W[(size_t)(k0 + j) * M + col];
        _Float16 h = (_Float16)x;
        h8[j] = h;
        l8[j] = (_Float16)(x - (float)h);
    }
    *(half8v*)&hi[(size_t)idx * 8] = h8;
    *(half8v*)&lo[(size_t)idx * 8] = l8;
}

// ---------------- GEMM1 (counted-vmcnt, 3 fp32 bufs, cooperative convert to
// 2 bf16 dbuf): C16[N,256] = fp16(X[N,512] @ W1). Each element converted ONCE.
__global__ __launch_bounds__(256, 3)
void k_gemm1d(const float* __restrict__ X, const unsigned short* __restrict__ Bh,
              const unsigned short* __restrict__ Bl, _Float16* __restrict__ C16, const int N) {
    constexpr int K = 512, M = 256, NT = K / 32;
    __shared__ char smem[40960];
    float* sXf = (float*)smem;
    unsigned short* sAh = (unsigned short*)(smem + 24576);
    unsigned short* sAl = (unsigned short*)(smem + 32768);
    const int tid = threadIdx.x;
    const int lane = tid & 63;
    const int w = tid >> 6;
    const int lm = lane & 15, lk = lane >> 4;
    const int row0 = blockIdx.x * 64;
    const int col0 = w * 64;

    const int kseg = (lane & 7) ^ ((lane >> 3) & 7);
    const int r0 = min(row0 + w * 16 + (lane >> 3), N - 1);
    const int r1 = min(row0 + w * 16 + 8 + (lane >> 3), N - 1);
    const size_t ga0 = (size_t)r0 * K + kseg * 4;
    const size_t ga1 = (size_t)r1 * K + kseg * 4;

    const int crow = w * 16 + (lane >> 2);
    const int ch = lane & 3;
    const int cu0 = ((2 * ch) ^ (crow & 7)) * 4;
    const int cu1 = ((2 * ch + 1) ^ (crow & 7)) * 4;
    const int cwo = crow * 32 + (ch ^ (crow & 3)) * 8;

    const unsigned short* bfh = Bh + ((size_t)(w * 4) * NT) * 512 + lane * 8;
    const unsigned short* bfl = Bl + ((size_t)(w * 4) * NT) * 512 + lane * 8;
    const int aoff = lm * 32 + ((lk ^ (lm & 3)) * 8);

    f32x4 acc[4][4];
    #pragma unroll
    for (int i = 0; i < 4; ++i)
        #pragma unroll
        for (int j = 0; j < 4; ++j) acc[i][j] = (f32x4){0.f, 0.f, 0.f, 0.f};

    auto stage = [&](int bi, int kk) {
        __builtin_amdgcn_global_load_lds((const AS1 void*)(X + ga0 + kk),
                                         (AS3 void*)(sXf + bi * 2048 + w * 512), 16, 0, 0);
        __builtin_amdgcn_global_load_lds((const AS1 void*)(X + ga1 + kk),
                                         (AS3 void*)(sXf + bi * 2048 + w * 512 + 256), 16, 0, 0);
    };

    auto convert = [&](int src, int dst) {
        const float* s = sXf + src * 2048 + crow * 32;
        f32x4 p0 = *(const f32x4*)(s + cu0);
        f32x4 p1 = *(const f32x4*)(s + cu1);
        float vv[8] = {p0.x, p0.y, p0.z, p0.w, p1.x, p1.y, p1.z, p1.w};
        short8 ah, al;
        #pragma unroll
        for (int j = 0; j < 8; ++j) {
            unsigned int uu = __builtin_bit_cast(unsigned int, vv[j]);
            ah[j] = (short)(uu >> 16);
            float hi_ = __builtin_bit_cast(float, uu & 0xFFFF0000u);
            al[j] = (short)f2bf_rne(vv[j] - hi_);
        }
        *(short8*)&sAh[dst * 2048 + cwo] = ah;
        *(short8*)&sAl[dst * 2048 + cwo] = al;
    };

    stage(0, 0); stage(1, 32); stage(2, 64);
    short8 bhf[4], blf[4];
    #pragma unroll
    for (int nf = 0; nf < 4; ++nf) {
        const size_t o = (size_t)nf * NT * 512;
        bhf[nf] = *(const short8*)(bfh + o);
        blf[nf] = *(const short8*)(bfl + o);
    }
    vm_wait<12>();
    convert(0, 0);
    lgkm0();
    __builtin_amdgcn_s_barrier();

    int b0 = 0;

#define G1D_BODY(T, VM)                                                         \
    {                                                                           \
        vm_wait<VM>();                                                          \
        __builtin_amdgcn_s_barrier();                                           \
        __builtin_amdgcn_sched_barrier(0);                                      \
        short8 bhn[4], bln[4];                                                  \
        _Pragma("unroll")                                                       \
        for (int nf = 0; nf < 4; ++nf) { bhn[nf] = bhf[nf]; bln[nf] = blf[nf]; }\
        if ((T) + 1 < NT) {                                                     \
            _Pragma("unroll")                                                   \
            for (int nf = 0; nf < 4; ++nf) {                                    \
                const size_t o = ((size_t)nf * NT + (T) + 1) * 512;             \
                bhn[nf] = *(const short8*)(bfh + o);                            \
                bln[nf] = *(const short8*)(bfl + o);                            \
            }                                                                   \
        }                                                                       \
        __builtin_amdgcn_sched_barrier(0);                                      \
        _Pragma("unroll")                                                       \
        for (int mf = 0; mf < 4; ++mf) {                                        \
            short8 ah = *(const short8*)&sAh[((T) & 1) * 2048 + aoff + mf * 512]; \
            short8 al = *(const short8*)&sAl[((T) & 1) * 2048 + aoff + mf * 512]; \
            _Pragma("unroll")                                                   \
            for (int nf = 0; nf < 4; ++nf) {                                    \
                acc[mf][nf] = __builtin_amdgcn_mfma_f32_16x16x32_bf16(ah, bhf[nf], acc[mf][nf], 0, 0, 0); \
                acc[mf][nf] = __builtin_amdgcn_mfma_f32_16x16x32_bf16(ah, blf[nf], acc[mf][nf], 0, 0, 0); \
                acc[mf][nf] = __builtin_amdgcn_mfma_f32_16x16x32_bf16(al, bhf[nf], acc[mf][nf], 0, 0, 0); \
            }                                                                   \
        }                                                                       \
        if ((T) + 1 < NT) {                                                     \
            int src = b0 + 1; if (src == 3) src = 0;                            \
            convert(src, ((T) + 1) & 1);                                        \
        }                                                                       \
        lgkm0();                                                                \
        __builtin_amdgcn_sched_barrier(0);                                      \
        __builtin_amdgcn_s_barrier();                                           \
        if ((T) + 3 < NT) stage(b0, ((T) + 3) * 32);                            \
        _Pragma("unroll")                                                       \
        for (int nf = 0; nf < 4; ++nf) { bhf[nf] = bhn[nf]; blf[nf] = bln[nf]; }\
        b0 = b0 + 1; if (b0 == 3) b0 = 0;                                       \
    }

    for (int t = 0; t < NT - 2; ++t) G1D_BODY(t, 10);
    G1D_BODY(NT - 2, 8);
    G1D_BODY(NT - 1, 8);
#undef G1D_BODY

    float* sc = (float*)smem;
    #pragma unroll
    for (int mf = 0; mf < 4; ++mf) {
        __syncthreads();
        #pragma unroll
        for (int nf = 0; nf < 4; ++nf)
            #pragma unroll
            for (int r = 0; r < 4; ++r) {
                const int rl = lk * 4 + r;
                const int col = col0 + nf * 16 + lm;
                sc[rl * M + (col ^ (lk << 3))] = acc[mf][nf][r];
            }
        __syncthreads();
        #pragma unroll
        for (int i = 0; i < 4; ++i) {
            const int idx = i * 256 + tid;
            const int rl = idx >> 6, u = idx & 63;
            const int grow = row0 + mf * 16 + rl;
            if (grow < N) {
                f32x4 v = *(const f32x4*)&sc[rl * M + ((u * 4) ^ (((rl >> 2) & 3) << 3))];
                half4v h;
                h[0] = (_Float16)v[0]; h[1] = (_Float16)v[1];
                h[2] = (_Float16)v[2]; h[3] = (_Float16)v[3];
                *(half4v*)&C16[(size_t)grow * M + u * 4] = h;
            }
        }
    }
}

// ---------------- GEMM fp16-MFMA (A exact fp16, B fp16 hi/lo, 2 MFMA passes,
// NO convert phase). counted-vmcnt, 3 fp16 A bufs. ----------------
template <int K, int NFW>
__global__ __launch_bounds__(256, 3)
void k_gemm_f16b(const _Float16* __restrict__ A16, const _Float16* __restrict__ Bh,
                 const _Float16* __restrict__ Bl, _Float16* __restrict__ Cout,
                 const int N) {
    constexpr int M = 64 * NFW;
    constexpr int NT = K / 32;
    constexpr int UPR = 16 * NFW;
    __shared__ char smem[16384];                 // 3 x 2048 halves (12 KB); epilogue 16*M*4 <= 16 KB
    _Float16* sX = (_Float16*)smem;
    const int tid = threadIdx.x;
    const int lane = tid & 63;
    const int w = tid >> 6;
    const int lm = lane & 15, lk = lane >> 4;
    const int row0 = blockIdx.x * 64;
    const int col0 = w * (16 * NFW);

    // staging with pre-swizzled global kseg (gemm_btc-proven pattern)
    const int kseg = (lane & 3) ^ ((lane >> 2) & 3);
    const int gr = min(row0 + w * 16 + (lane >> 2), N - 1);
    const size_t ga = (size_t)gr * K + kseg * 8;

    const int aoff = lm * 32 + ((lk ^ (lm & 3)) * 8);

    const _Float16* bfh = Bh + ((size_t)(w * NFW) * NT) * 512 + lane * 8;
    const _Float16* bfl = Bl + ((size_t)(w * NFW) * NT) * 512 + lane * 8;

    f32x4 acc[4][NFW];
    #pragma unroll
    for (int i = 0; i < 4; ++i)
        #pragma unroll
        for (int j = 0; j < NFW; ++j) acc[i][j] = (f32x4){0.f, 0.f, 0.f, 0.f};

    auto stage = [&](int bi, int kk) {
        __builtin_amdgcn_global_load_lds((const AS1 void*)(A16 + ga + kk),
                                         (AS3 void*)(sX + bi * 2048 + w * 512), 16, 0, 0);
    };

    stage(0, 0); stage(1, 32); stage(2, 64);

    half8v bhf[NFW], blf[NFW];
    #pragma unroll
    for (int nf = 0; nf < NFW; ++nf) {
        const size_t o = (size_t)nf * NT * 512;
        bhf[nf] = *(const half8v*)(bfh + o);
        blf[nf] = *(const half8v*)(bfl + o);
    }

    int bi = 0;

#define GF16_BODY(T, VM)                                                        \
    {                                                                           \
        vm_wait<VM>();                                                          \
        __builtin_amdgcn_s_barrier();                                           \
        __builtin_amdgcn_sched_barrier(0);                                      \
        half8v bhn[NFW], bln[NFW];                                              \
        _Pragma("unroll")                                                       \
        for (int nf = 0; nf < NFW; ++nf) { bhn[nf] = bhf[nf]; bln[nf] = blf[nf]; } \
        if ((T) + 1 < NT) {                                                     \
            _Pragma("unroll")                                                   \
            for (int nf = 0; nf < NFW; ++nf) {                                  \
                const size_t o = ((size_t)nf * NT + (T) + 1) * 512;             \
                bhn[nf] = *(const half8v*)(bfh + o);                            \
                bln[nf] = *(const half8v*)(bfl + o);                            \
            }                                                                   \
        }                                                                       \
        __builtin_amdgcn_sched_barrier(0);                                      \
        _Pragma("unroll")                                                       \
        for (int mf = 0; mf < 4; ++mf) {                                        \
            half8v av = *(const half8v*)&sX[bi * 2048 + aoff + mf * 512];       \
            _Pragma("unroll")                                                   \
            for (int nf = 0; nf < NFW; ++nf) {                                  \
                acc[mf][nf] = __builtin_amdgcn_mfma_f32_16x16x32_f16(av, bhf[nf], acc[mf][nf], 0, 0, 0); \
                acc[mf][nf] = __builtin_amdgcn_mfma_f32_16x16x32_f16(av, blf[nf], acc[mf][nf], 0, 0, 0); \
            }                                                                   \
        }                                                                       \
        lgkm0();                                                                \
        __builtin_amdgcn_sched_barrier(0);                                      \
        __builtin_amdgcn_s_barrier();                                           \
        if ((T) + 3 < NT) stage(bi, ((T) + 3) * 32);                            \
        _Pragma("unroll")                                                       \
        for (int nf = 0; nf < NFW; ++nf) { bhf[nf] = bhn[nf]; blf[nf] = bln[nf]; } \
        bi = bi + 1; if (bi == 3) bi = 0;                                       \
    }

    for (int t = 0; t < NT - 2; ++t) GF16_BODY(t, 2 * NFW + 2);
    GF16_BODY(NT - 2, 2 * NFW + 1);
    GF16_BODY(NT - 1, 2 * NFW);
#undef GF16_BODY

    float* sc = (float*)smem;
    #pragma unroll
    for (int mf = 0; mf < 4; ++mf) {
        __syncthreads();
        #pragma unroll
        for (int nf = 0; nf < NFW; ++nf)
            #pragma unroll
            for (int r = 0; r < 4; ++r) {
                const int rl = lk * 4 + r;
                const int col = col0 + nf * 16 + lm;
                sc[rl * M + (col ^ (lk << 3))] = acc[mf][nf][r];
            }
        __syncthreads();
        #pragma unroll
        for (int i = 0; i < (16 * UPR) / 256; ++i) {
            const int idx = i * 256 + tid;
            const int rl = idx / UPR, u = idx % UPR;
            const int gr2 = row0 + mf * 16 + rl;
            if (gr2 < N) {
                f32x4 v = *(const f32x4*)&sc[rl * M + ((u * 4) ^ (((rl >> 2) & 3) << 3))];
                half4v h;
                h[0] = (_Float16)v[0]; h[1] = (_Float16)v[1];
                h[2] = (_Float16)v[2]; h[3] = (_Float16)v[3];
                *(half4v*)&Cout[(size_t)gr2 * M + u * 4] = h;
            }
        }
    }
}

// ---------------- SpMM on fp16 input (F=256), wave-per-row, fused bias+relu,
// single fp16 output ----------------
__global__ __launch_bounds__(256)
void k_spmm256f(const int* __restrict__ rp, const int2* __restrict__ ev2,
                const _Float16* __restrict__ in16, const float* __restrict__ bias,
                _Float16* __restrict__ o16, int N) {
    const int lane = threadIdx.x & 63;
    int r = __builtin_amdgcn_readfirstlane(blockIdx.x * 4 + (threadIdx.x >> 6));
    if (r >= N) return;
    const int e0 = __builtin_amdgcn_readfirstlane(rp[r]);
    const int e1 = __builtin_amdgcn_readfirstlane(rp[r + 1]);
    f32x4 acc = {0.f, 0.f, 0.f, 0.f};
    const _Float16* base = in16 + lane * 4;

    #pragma unroll 4
    for (int e = e0; e < e1; ++e) {
        int2 p = ev2[e];
        half4v hv = *(const half4v*)(base + (size_t)p.x * 256);
        float val = __builtin_bit_cast(float, p.y);
        acc[0] = fmaf(val, (float)hv[0], acc[0]);
        acc[1] = fmaf(val, (float)hv[1], acc[1]);
        acc[2] = fmaf(val, (float)hv[2], acc[2]);
        acc[3] = fmaf(val, (float)hv[3], acc[3]);
    }

    f32x4 bv = *(const f32x4*)&bias[lane * 4];
    half4v h;
    #pragma unroll
    for (int j = 0; j < 4; ++j) {
        float o = fmaxf(acc[j] + bv[j], 0.f);
        h[j] = (_Float16)o;
    }
    *(half4v*)&o16[(size_t)r * 256 + lane * 4] = h;
}

// ---------------- SpMM F=128 on fp16 input + fused bias/relu + final dense ----------------
__global__ __launch_bounds__(256)
void k_spmm128f(const int* __restrict__ rp, const int2* __restrict__ ev2,
                const _Float16* __restrict__ in16, const float* __restrict__ b3,
                const float* __restrict__ Wd, const float* __restrict__ bd,
                float* __restrict__ out, int N) {
    __shared__ float Ws[H4 * NCLASS];
    __shared__ float hrow[4][H4];
    {
        int i = threadIdx.x * 8;
        *(f32x4*)&Ws[i] = *(const f32x4*)&Wd[i];
        *(f32x4*)&Ws[i + 4] = *(const f32x4*)&Wd[i + 4];
    }
    __syncthreads();

    const int lane = threadIdx.x & 63;
    const int w = threadIdx.x >> 6;
    int r = __builtin_amdgcn_readfirstlane(blockIdx.x * 4 + w);
    if (r >= N) return;
    const int e0 = __builtin_amdgcn_readfirstlane(rp[r]);
    const int e1 = __builtin_amdgcn_readfirstlane(rp[r + 1]);
    float a0 = 0.f, a1 = 0.f;
    const _Float16* base = in16 + lane * 2;

    #pragma unroll 4
    for (int e = e0; e < e1; ++e) {
        int2 p = ev2[e];
        half2v hv = *(const half2v*)(base + (size_t)p.x * 128);
        float v = __builtin_bit_cast(float, p.y);
        a0 = fmaf(v, (float)hv[0], a0);
        a1 = fmaf(v, (float)hv[1], a1);
    }

    float2 hb;
    hb.x = fmaxf(a0 + b3[lane * 2 + 0], 0.f);
    hb.y = fmaxf(a1 + b3[lane * 2 + 1], 0.f);
    *(float2*)&hrow[w][lane * 2] = hb;

    const int c = lane & 15, q = lane >> 4;
    float s = 0.f;
    #pragma unroll
    for (int k = q * 32; k < q * 32 + 32; ++k)
        s = fmaf(hrow[w][k], Ws[k * NCLASS + c], s);
    s += __shfl_xor(s, 16);
    s += __shfl_xor(s, 32);
    if (lane < 16) out[(size_t)r * NCLASS + lane] = s + bd[lane];
}

extern "C" void kernel_launch(void* const* d_in, const int* in_sizes, int n_in,
                              void* d_out, int out_size, void* d_ws, size_t ws_size,
                              hipStream_t stream) {
    const float* x  = (const float*)d_in[0];
    const int*   er = (const int*)d_in[1];
    const int*   ec = (const int*)d_in[2];
    const float* ev = (const float*)d_in[3];
    const float* W1 = (const float*)d_in[4];
    const float* b1 = (const float*)d_in[5];
    const float* W2 = (const float*)d_in[6];
    const float* b2 = (const float*)d_in[7];
    const float* W3 = (const float*)d_in[8];
    const float* b3 = (const float*)d_in[9];
    const float* Wd = (const float*)d_in[10];
    const float* bd = (const float*)d_in[11];
    float* out = (float*)d_out;

    const int N = in_sizes[0] / NFEAT;
    const int E = in_sizes[1];

    char* w = (char*)d_ws;
    auto alloc = [&](size_t bytes) { char* p = w; w += (bytes + 255) & ~(size_t)255; return p; };
    _Float16* C16 = (_Float16*)alloc((size_t)N * 256 * 2);
    _Float16* h16 = (_Float16*)alloc((size_t)N * 256 * 2);
    int* cnt  = (int*)alloc((size_t)N * 4);
    int* rp   = (int*)alloc((size_t)(N + 1) * 4);
    int* ofs  = (int*)alloc((size_t)N * 4);
    int2* ev2 = (int2*)alloc((size_t)E * 8);
    int* bsum = (int*)alloc(4096);
    unsigned short* W1h = (unsigned short*)alloc((size_t)NFEAT * H2 * 2);
    unsigned short* W1l = (unsigned short*)alloc((size_t)NFEAT * H2 * 2);
    _Float16* W2h = (_Float16*)alloc((size_t)H2 * H3 * 2);
    _Float16* W2l = (_Float16*)alloc((size_t)H2 * H3 * 2);
    _Float16* W3h = (_Float16*)alloc((size_t)H3 * H4 * 2);
    _Float16* W3l = (_Float16*)alloc((size_t)H3 * H4 * 2);

    const int nb = (N + 255) / 256;
    const int sliceSz = (N + 7) / 8;

    hipMemsetAsync(cnt, 0, (size_t)N * 4, stream);
    k_hist<<<1024, 256, 0, stream>>>(er, cnt, E);
    k_scan1<<<nb, 256, 0, stream>>>(cnt, rp, bsum, N);
    k_scan2<<<1, 512, 0, stream>>>(bsum, nb);
    k_scan3<<<nb, 256, 0, stream>>>(rp, ofs, bsum, cnt, N);
    k_scatter_sl<<<2048, 256, 0, stream>>>(er, ec, ev, ofs, ev2, E, sliceSz);

    k_packb<<<(NFEAT * H2 / 8 + 255) / 256, 256, 0, stream>>>(W1, W1h, W1l, NFEAT, H2);
    k_packb16<<<(H2 * H3 / 8 + 255) / 256, 256, 0, stream>>>(W2, W2h, W2l, H2, H3);
    k_packb16<<<(H3 * H4 / 8 + 255) / 256, 256, 0, stream>>>(W3, W3h, W3l, H3, H4);

    const int rgrid = (N + 63) / 64;
    const int sgrid = (N + 3) / 4;

    k_gemm1d<<<rgrid, 256, 0, stream>>>(x, W1h, W1l, C16, N);
    k_spmm256f<<<sgrid, 256, 0, stream>>>(rp, ev2, C16, b1, h16, N);

    k_gemm_f16b<H2, 4><<<rgrid, 256, 0, stream>>>(h16, W2h, W2l, C16, N);
    k_spmm256f<<<sgrid, 256, 0, stream>>>(rp, ev2, C16, b2, h16, N);

    k_gemm_f16b<H3, 2><<<rgrid, 256, 0, stream>>>(h16, W3h, W3l, C16, N);
    k_spmm128f<<<sgrid, 256, 0, stream>>>(rp, ev2, C16, b3, Wd, bd, out, N);
}